// Round 1
// baseline (8232.267 us; speedup 1.0000x reference)
//
#include <hip/hip_runtime.h>
#include <math.h>

#define N_TOK 13320
#define B_BATCH 240
#define DMODEL 512
#define NHEAD 8
#define DHEAD 64
#define DINNER 2048
#define LN_EPS 1e-5f

// ---------------- offsets (exclusive cumsum of num_objs) ----------------
__global__ void k_offsets(const int* __restrict__ num_objs, int* __restrict__ offs) {
    if (blockIdx.x == 0 && threadIdx.x == 0) {
        int acc = 0;
        for (int b = 0; b < B_BATCH; ++b) { offs[b] = acc; acc += num_objs[b]; }
    }
}

// ---------------- f32 tiled GEMM: C = A[M,K] @ W[K,N] + bias (+res) (relu) ----
// 64x64 tile, 256 threads, 4x4 per thread, K-step 16.
template<int RELU, int RES>
__global__ __launch_bounds__(256)
void k_gemm(const float* __restrict__ A, const float* __restrict__ W,
            const float* __restrict__ bias, const float* __restrict__ res,
            float* __restrict__ C, int M, int K, int N) {
    __shared__ float As[16][65];   // As[k][m]
    __shared__ float Bs[16][65];   // Bs[k][n]
    int tid = threadIdx.x;
    int tx = tid & 15, ty = tid >> 4;
    int row0 = blockIdx.x * 64;
    int col0 = blockIdx.y * 64;
    float acc[4][4] = {};
    for (int k0 = 0; k0 < K; k0 += 16) {
#pragma unroll
        for (int i = 0; i < 4; ++i) {
            int idx = tid + i * 256;          // 0..1023 -> 64x16 A tile
            int m = idx >> 4, kk = idx & 15;
            int gr = row0 + m;
            As[kk][m] = (gr < M) ? A[(size_t)gr * K + k0 + kk] : 0.f;
        }
#pragma unroll
        for (int i = 0; i < 4; ++i) {
            int idx = tid + i * 256;          // 16x64 B tile
            int kk = idx >> 6, n = idx & 63;
            Bs[kk][n] = W[(size_t)(k0 + kk) * N + col0 + n];
        }
        __syncthreads();
#pragma unroll
        for (int kk = 0; kk < 16; ++kk) {
            float a[4], b[4];
#pragma unroll
            for (int i = 0; i < 4; ++i) a[i] = As[kk][ty * 4 + i];
#pragma unroll
            for (int j = 0; j < 4; ++j) b[j] = Bs[kk][tx * 4 + j];
#pragma unroll
            for (int i = 0; i < 4; ++i)
#pragma unroll
                for (int j = 0; j < 4; ++j) acc[i][j] = fmaf(a[i], b[j], acc[i][j]);
        }
        __syncthreads();
    }
#pragma unroll
    for (int i = 0; i < 4; ++i) {
        int r = row0 + ty * 4 + i;
        if (r >= M) continue;
#pragma unroll
        for (int j = 0; j < 4; ++j) {
            int c = col0 + tx * 4 + j;
            float v = acc[i][j] + bias[c];
            if (RES) v += res[(size_t)r * N + c];
            if (RELU) v = fmaxf(v, 0.f);
            C[(size_t)r * N + c] = v;
        }
    }
}

// ---------------- segment attention: one block per (batch, head) -------------
__global__ __launch_bounds__(256)
void k_attn(const float* __restrict__ Q, const float* __restrict__ K,
            const float* __restrict__ V, const int* __restrict__ offs,
            const int* __restrict__ num_objs, float* __restrict__ CTX) {
    int b = blockIdx.x, h = blockIdx.y;
    int L = num_objs[b];
    int off = offs[b];
    __shared__ float Ks[95][65];
    __shared__ float Vs[95][65];
    __shared__ float Sw[4][96];
    __shared__ float Qw[4][64];
    int tid = threadIdx.x;
    for (int idx = tid; idx < L * 64; idx += 256) {
        int j = idx >> 6, d = idx & 63;
        size_t g = (size_t)(off + j) * DMODEL + h * DHEAD + d;
        Ks[j][d] = K[g];
        Vs[j][d] = V[g];
    }
    __syncthreads();
    int wave = tid >> 6, lane = tid & 63;
    int nIter = (L + 3) >> 2;
    for (int it = 0; it < nIter; ++it) {
        int i = it * 4 + wave;
        bool act = (i < L);
        if (act) Qw[wave][lane] = Q[(size_t)(off + i) * DMODEL + h * DHEAD + lane];
        __syncthreads();
        if (act) {
            int j0 = lane, j1 = lane + 64;
            int cj0 = (j0 < L) ? j0 : 0;
            int cj1 = (j1 < L) ? j1 : 0;
            float a0 = 0.f, a1 = 0.f;
#pragma unroll
            for (int d = 0; d < 64; ++d) {
                float q = Qw[wave][d];
                a0 = fmaf(q, Ks[cj0][d], a0);
                a1 = fmaf(q, Ks[cj1][d], a1);
            }
            float s0 = (j0 < L) ? a0 * 0.125f : -1e30f;
            float s1 = (j1 < L) ? a1 * 0.125f : -1e30f;
            float m = fmaxf(s0, s1);
            for (int o = 32; o > 0; o >>= 1) m = fmaxf(m, __shfl_xor(m, o));
            float p0 = (j0 < L) ? __expf(s0 - m) : 0.f;
            float p1 = (j1 < L) ? __expf(s1 - m) : 0.f;
            float sum = p0 + p1;
            for (int o = 32; o > 0; o >>= 1) sum += __shfl_xor(sum, o);
            Sw[wave][j0] = p0;
            if (j1 < 96) Sw[wave][j1] = p1;
            float inv = 1.f / sum;
            float accv = 0.f;
            for (int j = 0; j < L; ++j) accv = fmaf(Sw[wave][j], Vs[j][lane], accv);
            CTX[(size_t)(off + i) * DMODEL + h * DHEAD + lane] = accv * inv;
        }
        __syncthreads();
    }
}

// ---------------- LayerNorm over 512 cols, one wave per row ------------------
template<int ACCUM>
__global__ __launch_bounds__(64)
void k_ln(const float* __restrict__ X, const float* __restrict__ g,
          const float* __restrict__ be, float* __restrict__ out) {
    int row = blockIdx.x;
    int lane = threadIdx.x;
    const float4* x4 = (const float4*)(X + (size_t)row * DMODEL);
    float4 v0 = x4[lane];
    float4 v1 = x4[lane + 64];
    float s = v0.x + v0.y + v0.z + v0.w + v1.x + v1.y + v1.z + v1.w;
    for (int o = 32; o > 0; o >>= 1) s += __shfl_xor(s, o);
    float mean = s * (1.f / 512.f);
    float d0 = v0.x - mean, d1 = v0.y - mean, d2 = v0.z - mean, d3 = v0.w - mean;
    float d4 = v1.x - mean, d5 = v1.y - mean, d6 = v1.z - mean, d7 = v1.w - mean;
    float vs = d0*d0 + d1*d1 + d2*d2 + d3*d3 + d4*d4 + d5*d5 + d6*d6 + d7*d7;
    for (int o = 32; o > 0; o >>= 1) vs += __shfl_xor(vs, o);
    float rstd = rsqrtf(vs * (1.f / 512.f) + LN_EPS);
    const float4* g4 = (const float4*)g;
    const float4* b4 = (const float4*)be;
    float4 ga = g4[lane], gb = g4[lane + 64];
    float4 ba = b4[lane], bb = b4[lane + 64];
    float4 o0, o1;
    o0.x = d0 * rstd * ga.x + ba.x;
    o0.y = d1 * rstd * ga.y + ba.y;
    o0.z = d2 * rstd * ga.z + ba.z;
    o0.w = d3 * rstd * ga.w + ba.w;
    o1.x = d4 * rstd * gb.x + bb.x;
    o1.y = d5 * rstd * gb.y + bb.y;
    o1.z = d6 * rstd * gb.z + bb.z;
    o1.w = d7 * rstd * gb.w + bb.w;
    float4* out4 = (float4*)(out + (size_t)row * DMODEL);
    if (ACCUM) {
        float4 e0 = out4[lane], e1 = out4[lane + 64];
        o0.x += e0.x; o0.y += e0.y; o0.z += e0.z; o0.w += e0.w;
        o1.x += e1.x; o1.y += e1.y; o1.z += e1.z; o1.w += e1.w;
    }
    out4[lane] = o0;
    out4[lane + 64] = o1;
}

// ---------------- driver ------------------------------------------------------
extern "C" void kernel_launch(void* const* d_in, const int* in_sizes, int n_in,
                              void* d_out, int out_size, void* d_ws, size_t ws_size,
                              hipStream_t stream) {
    const float* vis = (const float*)d_in[0];
    const float* txt = (const float*)d_in[1];
    const float* Wq  = (const float*)d_in[2];
    const float* bq  = (const float*)d_in[3];
    const float* Wk  = (const float*)d_in[4];
    const float* bk  = (const float*)d_in[5];
    const float* Wv  = (const float*)d_in[6];
    const float* bv  = (const float*)d_in[7];
    const float* Wo  = (const float*)d_in[8];
    const float* bo  = (const float*)d_in[9];
    const float* g1  = (const float*)d_in[10];
    const float* be1 = (const float*)d_in[11];
    const float* W1  = (const float*)d_in[12];
    const float* b1  = (const float*)d_in[13];
    const float* W2  = (const float*)d_in[14];
    const float* b2  = (const float*)d_in[15];
    const float* g2  = (const float*)d_in[16];
    const float* be2 = (const float*)d_in[17];
    const int* num_objs = (const int*)d_in[18];

    float* ws   = (float*)d_ws;
    float* Hbuf = ws;                                  // N_TOK * 2048
    float* Qb   = ws + (size_t)N_TOK * DINNER;         // N_TOK * 512
    float* Kb   = Qb + (size_t)N_TOK * DMODEL;
    float* Vb   = Kb + (size_t)N_TOK * DMODEL;
    float* Cb   = Vb + (size_t)N_TOK * DMODEL;
    int*   offs = (int*)(Cb + (size_t)N_TOK * DMODEL);

    float* outv = (float*)d_out;                       // visual output [N,512]
    float* outt = outv + (size_t)N_TOK * DMODEL;       // textual output [N,512]

    k_offsets<<<1, 1, 0, stream>>>(num_objs, offs);

    struct Enc { const float* q; const float* kv; int p; float* dst; int accum; };
    Enc encs[4] = {
        { txt, txt, 1, outt, 0 },   // tsa
        { txt, vis, 3, outt, 1 },   // tca
        { vis, vis, 0, outv, 0 },   // vsa
        { vis, txt, 2, outv, 1 },   // vca
    };

    dim3 blk(256);
    int mb = (N_TOK + 63) / 64;
    for (int e = 0; e < 4; ++e) {
        const Enc& E = encs[e];
        size_t pW  = (size_t)E.p * DMODEL * DMODEL;
        size_t pB  = (size_t)E.p * DMODEL;
        size_t pW1 = (size_t)E.p * DMODEL * DINNER;
        size_t pB1 = (size_t)E.p * DINNER;

        k_gemm<0,0><<<dim3(mb, 8),  blk, 0, stream>>>(E.q,  Wq + pW, bq + pB, nullptr, Qb, N_TOK, DMODEL, DMODEL);
        k_gemm<0,0><<<dim3(mb, 8),  blk, 0, stream>>>(E.kv, Wk + pW, bk + pB, nullptr, Kb, N_TOK, DMODEL, DMODEL);
        k_gemm<0,0><<<dim3(mb, 8),  blk, 0, stream>>>(E.kv, Wv + pW, bv + pB, nullptr, Vb, N_TOK, DMODEL, DMODEL);
        k_attn<<<dim3(B_BATCH, NHEAD), blk, 0, stream>>>(Qb, Kb, Vb, offs, num_objs, Cb);
        // O = CTX @ Wo + bo + q_in   -> Qb (reused)
        k_gemm<0,1><<<dim3(mb, 8),  blk, 0, stream>>>(Cb, Wo + pW, bo + pB, E.q, Qb, N_TOK, DMODEL, DMODEL);
        // OUT1 = LN1(O) -> Kb (reused)
        k_ln<0><<<N_TOK, 64, 0, stream>>>(Qb, g1 + pB, be1 + pB, Kb);
        // H = relu(OUT1 @ W1 + b1) -> Hbuf
        k_gemm<1,0><<<dim3(mb, 32), blk, 0, stream>>>(Kb, W1 + pW1, b1 + pB1, nullptr, Hbuf, N_TOK, DMODEL, DINNER);
        // F = H @ W2 + b2 + OUT1 -> Vb (reused)
        k_gemm<0,1><<<dim3(mb, 8),  blk, 0, stream>>>(Hbuf, W2 + pW1, b2 + pB, Kb, Vb, N_TOK, DINNER, DMODEL);
        // OUT2 = LN2(F) -> dst (write or accumulate)
        if (E.accum) k_ln<1><<<N_TOK, 64, 0, stream>>>(Vb, g2 + pB, be2 + pB, E.dst);
        else         k_ln<0><<<N_TOK, 64, 0, stream>>>(Vb, g2 + pB, be2 + pB, E.dst);
    }
}

// Round 2
// 1754.065 us; speedup vs baseline: 4.6932x; 4.6932x over previous
//
#include <hip/hip_runtime.h>
#include <math.h>

#define M_REAL 13320
#define M_PAD  13440          // 105 * 128
#define B_BATCH 240
#define DMODEL 512
#define DINNER 2048
#define LN_EPS 1e-5f

typedef __attribute__((ext_vector_type(8))) short short8;   // bf16x8 frag (4 VGPR)
typedef __attribute__((ext_vector_type(4))) float f32x4;    // MFMA acc

__device__ __forceinline__ ushort f2bf(float f) {
    unsigned u = __float_as_uint(f);
    u += 0x7FFFu + ((u >> 16) & 1u);           // RNE
    return (ushort)(u >> 16);
}
__device__ __forceinline__ float bf2f(ushort h) {
    return __uint_as_float(((unsigned)h) << 16);
}

typedef __attribute__((address_space(3))) unsigned int lds_u32;
typedef __attribute__((address_space(1))) unsigned int glb_u32;
__device__ __forceinline__ void gl_lds16(const ushort* g, ushort* l) {
    __builtin_amdgcn_global_load_lds((glb_u32*)g, (lds_u32*)l, 16, 0, 0);
}

// ---------------- offsets ----------------
__global__ void k_offsets(const int* __restrict__ num_objs, int* __restrict__ offs) {
    if (threadIdx.x == 0) {
        int acc = 0;
        for (int b = 0; b < B_BATCH; ++b) { offs[b] = acc; acc += num_objs[b]; }
    }
}

// ---------------- f32 [M_REAL,512] -> bf16 [M_PAD,512], zero pad rows -------
__global__ __launch_bounds__(256)
void k_cvt_in(const float* __restrict__ src, ushort* __restrict__ dst) {
    int idx = blockIdx.x * 256 + threadIdx.x;   // one thread = 8 elems
    int row = idx >> 6;
    short8 o;
    if (row < M_REAL) {
        const float4* s = (const float4*)src + (size_t)idx * 2;
        float4 a = s[0], b = s[1];
        o[0] = (short)f2bf(a.x); o[1] = (short)f2bf(a.y);
        o[2] = (short)f2bf(a.z); o[3] = (short)f2bf(a.w);
        o[4] = (short)f2bf(b.x); o[5] = (short)f2bf(b.y);
        o[6] = (short)f2bf(b.z); o[7] = (short)f2bf(b.w);
    } else {
        o = (short8)0;
    }
    ((short8*)dst)[idx] = o;
}

// ---------------- weight transpose+cvt: f32 [R,C] -> bf16 [C,R], z-batched --
__global__ __launch_bounds__(256)
void k_wt(const float* __restrict__ src, ushort* __restrict__ dst, int R, int C) {
    __shared__ float t[32][33];
    const float* s = src + (size_t)blockIdx.z * R * C;
    ushort* d = dst + (size_t)blockIdx.z * R * C;
    int tx = threadIdx.x & 31, ty = threadIdx.x >> 5;   // 32 x 8
    int r0 = blockIdx.y * 32, c0 = blockIdx.x * 32;
#pragma unroll
    for (int i = 0; i < 4; ++i)
        t[ty + i * 8][tx] = s[(size_t)(r0 + ty + i * 8) * C + c0 + tx];
    __syncthreads();
#pragma unroll
    for (int i = 0; i < 4; ++i)
        d[(size_t)(c0 + ty + i * 8) * R + r0 + tx] = f2bf(t[tx][ty + i * 8]);
}

// ---------------- bf16 MFMA GEMM: C = A[M_PAD,K] @ Wt[N,K]^T + bias ... ------
// 128x128 tile, BK=64, 256 thr (4 waves 2x2), 16x16x32 bf16 MFMA.
// LDS linear dest for global_load_lds; source pre-swizzled so ds_read uses
// byte ^= ((row&7)<<4) chunk swizzle (conflict-free b128 reads).
enum { EPI_BF16 = 0, EPI_BF16_RELU = 1, EPI_F32_RESF32 = 2, EPI_F32_RESBF16 = 3 };

template<int MODE>
__global__ __launch_bounds__(256)
void k_gemm16(const ushort* __restrict__ A, const ushort* __restrict__ Wt,
              const float* __restrict__ bias, const void* __restrict__ resv,
              void* __restrict__ Cv, int K, int lda, int ldc, int Mreal, int colBase) {
    __shared__ ushort As[128 * 64];
    __shared__ ushort Bs[128 * 64];
    const int tid = threadIdx.x;
    const int row0 = blockIdx.x * 128;
    const int col0 = blockIdx.y * 128;
    const int lane = tid & 63, wid = tid >> 6;
    const int wr = wid >> 1, wc = wid & 1;
    const int fr = lane & 15, fq = lane >> 4;

    int srow[4], scol[4], soff[4];
#pragma unroll
    for (int r = 0; r < 4; ++r) {
        int off = tid * 16 + r * 4096;          // LDS byte offset (linear dest)
        int row = off >> 7;                     // 0..127
        int cp  = (off >> 4) & 7;               // chunk pos in row
        soff[r] = off;
        srow[r] = row;
        scol[r] = (cp ^ (row & 7)) * 8;         // pre-swizzled global k-chunk
    }

    f32x4 acc[4][4];
#pragma unroll
    for (int m = 0; m < 4; ++m)
#pragma unroll
        for (int n = 0; n < 4; ++n) acc[m][n] = (f32x4){0.f, 0.f, 0.f, 0.f};

    const int nk = K >> 6;
    for (int kt = 0; kt < nk; ++kt) {
        const int k0 = kt << 6;
#pragma unroll
        for (int r = 0; r < 4; ++r)
            gl_lds16(A + (size_t)(row0 + srow[r]) * lda + k0 + scol[r],
                     (ushort*)((char*)As + soff[r]));
#pragma unroll
        for (int r = 0; r < 4; ++r)
            gl_lds16(Wt + (size_t)(col0 + srow[r]) * K + k0 + scol[r],
                     (ushort*)((char*)Bs + soff[r]));
        __syncthreads();
#pragma unroll
        for (int kk = 0; kk < 2; ++kk) {
            short8 av[4], bv[4];
#pragma unroll
            for (int m = 0; m < 4; ++m) {
                int row = wr * 64 + m * 16 + fr;
                int byte = row * 128 + (((kk * 4 + fq) ^ (row & 7)) << 4);
                av[m] = *(const short8*)((const char*)As + byte);
            }
#pragma unroll
            for (int n = 0; n < 4; ++n) {
                int row = wc * 64 + n * 16 + fr;
                int byte = row * 128 + (((kk * 4 + fq) ^ (row & 7)) << 4);
                bv[n] = *(const short8*)((const char*)Bs + byte);
            }
#pragma unroll
            for (int m = 0; m < 4; ++m)
#pragma unroll
                for (int n = 0; n < 4; ++n)
                    acc[m][n] = __builtin_amdgcn_mfma_f32_16x16x32_bf16(av[m], bv[n], acc[m][n], 0, 0, 0);
        }
        __syncthreads();
    }

    // epilogue: C/D layout col=lane&15, row=(lane>>4)*4+i
#pragma unroll
    for (int m = 0; m < 4; ++m) {
#pragma unroll
        for (int n = 0; n < 4; ++n) {
            int cN = col0 + wc * 64 + n * 16 + fr;      // GEMM-local col
            float bsv = bias[cN];
#pragma unroll
            for (int i = 0; i < 4; ++i) {
                int r = row0 + wr * 64 + m * 16 + fq * 4 + i;
                size_t oidx = (size_t)r * ldc + colBase + cN;
                float v = acc[m][n][i] + bsv;
                if (MODE == EPI_BF16) {
                    ((ushort*)Cv)[oidx] = f2bf(v);
                } else if (MODE == EPI_BF16_RELU) {
                    ((ushort*)Cv)[oidx] = f2bf(fmaxf(v, 0.f));
                } else if (MODE == EPI_F32_RESF32) {
                    if (r < Mreal) v += ((const float*)resv)[oidx];
                    ((float*)Cv)[oidx] = v;
                } else {
                    v += bf2f(((const ushort*)resv)[oidx]);
                    ((float*)Cv)[oidx] = v;
                }
            }
        }
    }
}

// ---------------- segment attention (bf16 in/out, f32 math) ------------------
__global__ __launch_bounds__(256)
void k_attn(const ushort* __restrict__ QKV, const int* __restrict__ offs,
            const int* __restrict__ num_objs, ushort* __restrict__ CTX) {
    int b = blockIdx.x, h = blockIdx.y;
    int L = num_objs[b];
    int off = offs[b];
    __shared__ float Ks[95][65];
    __shared__ float Vs[95][65];
    __shared__ float Sw[4][96];
    __shared__ float Qw[4][64];
    int tid = threadIdx.x;
    for (int idx = tid; idx < L * 64; idx += 256) {
        int j = idx >> 6, d = idx & 63;
        size_t g = (size_t)(off + j) * 1536 + h * 64 + d;
        Ks[j][d] = bf2f(QKV[g + 512]);
        Vs[j][d] = bf2f(QKV[g + 1024]);
    }
    __syncthreads();
    int wave = tid >> 6, lane = tid & 63;
    int nIter = (L + 3) >> 2;
    for (int it = 0; it < nIter; ++it) {
        int i = it * 4 + wave;
        bool act = (i < L);
        if (act) Qw[wave][lane] = bf2f(QKV[(size_t)(off + i) * 1536 + h * 64 + lane]);
        __syncthreads();
        if (act) {
            int j0 = lane, j1 = lane + 64;
            int cj0 = (j0 < L) ? j0 : 0;
            int cj1 = (j1 < L) ? j1 : 0;
            float a0 = 0.f, a1 = 0.f;
#pragma unroll
            for (int d = 0; d < 64; ++d) {
                float q = Qw[wave][d];
                a0 = fmaf(q, Ks[cj0][d], a0);
                a1 = fmaf(q, Ks[cj1][d], a1);
            }
            float s0 = (j0 < L) ? a0 * 0.125f : -1e30f;
            float s1 = (j1 < L) ? a1 * 0.125f : -1e30f;
            float m = fmaxf(s0, s1);
            for (int o = 32; o > 0; o >>= 1) m = fmaxf(m, __shfl_xor(m, o));
            float p0 = (j0 < L) ? __expf(s0 - m) : 0.f;
            float p1 = (j1 < L) ? __expf(s1 - m) : 0.f;
            float sum = p0 + p1;
            for (int o = 32; o > 0; o >>= 1) sum += __shfl_xor(sum, o);
            Sw[wave][j0] = p0;
            if (j1 < 96) Sw[wave][j1] = p1;
            float inv = 1.f / sum;
            float accv = 0.f;
            for (int j = 0; j < L; ++j) accv = fmaf(Sw[wave][j], Vs[j][lane], accv);
            CTX[(size_t)(off + i) * 512 + h * 64 + lane] = f2bf(accv * inv);
        }
        __syncthreads();
    }
}

// ---------------- LayerNorm (512 cols, one wave per row) ---------------------
__global__ __launch_bounds__(64)
void k_ln_bf16out(const float* __restrict__ X, const float* __restrict__ g,
                  const float* __restrict__ be, ushort* __restrict__ out) {
    int row = blockIdx.x, lane = threadIdx.x;
    const float4* x4 = (const float4*)(X + (size_t)row * DMODEL);
    float4 v0 = x4[2 * lane], v1 = x4[2 * lane + 1];
    float s = v0.x + v0.y + v0.z + v0.w + v1.x + v1.y + v1.z + v1.w;
    for (int o = 32; o > 0; o >>= 1) s += __shfl_xor(s, o);
    float mean = s * (1.f / 512.f);
    float d0 = v0.x - mean, d1 = v0.y - mean, d2 = v0.z - mean, d3 = v0.w - mean;
    float d4 = v1.x - mean, d5 = v1.y - mean, d6 = v1.z - mean, d7 = v1.w - mean;
    float vs = d0*d0 + d1*d1 + d2*d2 + d3*d3 + d4*d4 + d5*d5 + d6*d6 + d7*d7;
    for (int o = 32; o > 0; o >>= 1) vs += __shfl_xor(vs, o);
    float rstd = rsqrtf(vs * (1.f / 512.f) + LN_EPS);
    const float4* g4 = (const float4*)g;
    const float4* b4 = (const float4*)be;
    float4 ga = g4[2 * lane], gb = g4[2 * lane + 1];
    float4 ba = b4[2 * lane], bb = b4[2 * lane + 1];
    short8 o8;
    o8[0] = (short)f2bf(d0 * rstd * ga.x + ba.x);
    o8[1] = (short)f2bf(d1 * rstd * ga.y + ba.y);
    o8[2] = (short)f2bf(d2 * rstd * ga.z + ba.z);
    o8[3] = (short)f2bf(d3 * rstd * ga.w + ba.w);
    o8[4] = (short)f2bf(d4 * rstd * gb.x + bb.x);
    o8[5] = (short)f2bf(d5 * rstd * gb.y + bb.y);
    o8[6] = (short)f2bf(d6 * rstd * gb.z + bb.z);
    o8[7] = (short)f2bf(d7 * rstd * gb.w + bb.w);
    ((short8*)(out + (size_t)row * DMODEL))[lane] = o8;
}

template<int ACCUM>
__global__ __launch_bounds__(64)
void k_ln_f32out(const float* __restrict__ X, const float* __restrict__ g,
                 const float* __restrict__ be, float* __restrict__ out) {
    int row = blockIdx.x, lane = threadIdx.x;
    const float4* x4 = (const float4*)(X + (size_t)row * DMODEL);
    float4 v0 = x4[2 * lane], v1 = x4[2 * lane + 1];
    float s = v0.x + v0.y + v0.z + v0.w + v1.x + v1.y + v1.z + v1.w;
    for (int o = 32; o > 0; o >>= 1) s += __shfl_xor(s, o);
    float mean = s * (1.f / 512.f);
    float d0 = v0.x - mean, d1 = v0.y - mean, d2 = v0.z - mean, d3 = v0.w - mean;
    float d4 = v1.x - mean, d5 = v1.y - mean, d6 = v1.z - mean, d7 = v1.w - mean;
    float vs = d0*d0 + d1*d1 + d2*d2 + d3*d3 + d4*d4 + d5*d5 + d6*d6 + d7*d7;
    for (int o = 32; o > 0; o >>= 1) vs += __shfl_xor(vs, o);
    float rstd = rsqrtf(vs * (1.f / 512.f) + LN_EPS);
    const float4* g4 = (const float4*)g;
    const float4* b4 = (const float4*)be;
    float4 ga = g4[2 * lane], gb = g4[2 * lane + 1];
    float4 ba = b4[2 * lane], bb = b4[2 * lane + 1];
    float4 o0, o1;
    o0.x = d0 * rstd * ga.x + ba.x;  o0.y = d1 * rstd * ga.y + ba.y;
    o0.z = d2 * rstd * ga.z + ba.z;  o0.w = d3 * rstd * ga.w + ba.w;
    o1.x = d4 * rstd * gb.x + bb.x;  o1.y = d5 * rstd * gb.y + bb.y;
    o1.z = d6 * rstd * gb.z + bb.z;  o1.w = d7 * rstd * gb.w + bb.w;
    float4* out4 = (float4*)(out + (size_t)row * DMODEL);
    if (ACCUM) {
        float4 e0 = out4[2 * lane], e1 = out4[2 * lane + 1];
        o0.x += e0.x; o0.y += e0.y; o0.z += e0.z; o0.w += e0.w;
        o1.x += e1.x; o1.y += e1.y; o1.z += e1.z; o1.w += e1.w;
    }
    out4[2 * lane] = o0;
    out4[2 * lane + 1] = o1;
}

// ---------------- driver ------------------------------------------------------
extern "C" void kernel_launch(void* const* d_in, const int* in_sizes, int n_in,
                              void* d_out, int out_size, void* d_ws, size_t ws_size,
                              hipStream_t stream) {
    const float* vis = (const float*)d_in[0];
    const float* txt = (const float*)d_in[1];
    const float* Wq  = (const float*)d_in[2];
    const float* bq  = (const float*)d_in[3];
    const float* Wk  = (const float*)d_in[4];
    const float* bk  = (const float*)d_in[5];
    const float* Wv  = (const float*)d_in[6];
    const float* bv  = (const float*)d_in[7];
    const float* Wo  = (const float*)d_in[8];
    const float* bo  = (const float*)d_in[9];
    const float* g1  = (const float*)d_in[10];
    const float* be1 = (const float*)d_in[11];
    const float* W1  = (const float*)d_in[12];
    const float* b1  = (const float*)d_in[13];
    const float* W2  = (const float*)d_in[14];
    const float* b2  = (const float*)d_in[15];
    const float* g2  = (const float*)d_in[16];
    const float* be2 = (const float*)d_in[17];
    const int* num_objs = (const int*)d_in[18];

    // ---- workspace layout (bf16 buffers padded to M_PAD rows) ----
    char* p = (char*)d_ws;
    ushort* vis16 = (ushort*)p;               p += (size_t)M_PAD * 512 * 2;
    ushort* txt16 = (ushort*)p;               p += (size_t)M_PAD * 512 * 2;
    ushort* wq16  = (ushort*)p;               p += (size_t)4 * 512 * 512 * 2;
    ushort* wk16  = (ushort*)p;               p += (size_t)4 * 512 * 512 * 2;
    ushort* wv16  = (ushort*)p;               p += (size_t)4 * 512 * 512 * 2;
    ushort* wo16  = (ushort*)p;               p += (size_t)4 * 512 * 512 * 2;
    ushort* w116  = (ushort*)p;               p += (size_t)4 * 512 * 2048 * 2;
    ushort* w216  = (ushort*)p;               p += (size_t)4 * 512 * 2048 * 2;
    ushort* QKV16 = (ushort*)p;               p += (size_t)M_PAD * 1536 * 2;
    ushort* CTX16 = (ushort*)p;               p += (size_t)M_PAD * 512 * 2;
    ushort* O116  = (ushort*)p;               p += (size_t)M_PAD * 512 * 2;
    ushort* H16   = (ushort*)p;               p += (size_t)M_PAD * 2048 * 2;
    float*  Ob    = (float*)p;                p += (size_t)M_PAD * 512 * 4;
    int*    offs  = (int*)p;                  p += 1024;

    float* outv = (float*)d_out;
    float* outt = outv + (size_t)M_REAL * DMODEL;

    k_offsets<<<1, 64, 0, stream>>>(num_objs, offs);
    k_cvt_in<<<3360, 256, 0, stream>>>(vis, vis16);
    k_cvt_in<<<3360, 256, 0, stream>>>(txt, txt16);
    k_wt<<<dim3(16, 16, 4), 256, 0, stream>>>(Wq, wq16, 512, 512);
    k_wt<<<dim3(16, 16, 4), 256, 0, stream>>>(Wk, wk16, 512, 512);
    k_wt<<<dim3(16, 16, 4), 256, 0, stream>>>(Wv, wv16, 512, 512);
    k_wt<<<dim3(16, 16, 4), 256, 0, stream>>>(Wo, wo16, 512, 512);
    k_wt<<<dim3(64, 16, 4), 256, 0, stream>>>(W1, w116, 512, 2048);
    k_wt<<<dim3(16, 64, 4), 256, 0, stream>>>(W2, w216, 2048, 512);

    struct Enc { const ushort* q16; const ushort* kv16; const float* qf32; int p; float* dst; int accum; };
    Enc encs[4] = {
        { txt16, txt16, txt, 1, outt, 0 },   // tsa
        { txt16, vis16, txt, 3, outt, 1 },   // tca
        { vis16, vis16, vis, 0, outv, 0 },   // vsa
        { vis16, txt16, vis, 2, outv, 1 },   // vca
    };

    const int MB = M_PAD / 128;   // 105
    for (int e = 0; e < 4; ++e) {
        const Enc& E = encs[e];
        size_t pW  = (size_t)E.p * 512 * 512;
        size_t pB  = (size_t)E.p * 512;
        size_t pW1 = (size_t)E.p * 512 * 2048;
        size_t pB1 = (size_t)E.p * 2048;

        k_gemm16<EPI_BF16><<<dim3(MB, 4), 256, 0, stream>>>(
            E.q16,  wq16 + pW, bq + pB, nullptr, QKV16, 512, 512, 1536, M_PAD, 0);
        k_gemm16<EPI_BF16><<<dim3(MB, 4), 256, 0, stream>>>(
            E.kv16, wk16 + pW, bk + pB, nullptr, QKV16, 512, 512, 1536, M_PAD, 512);
        k_gemm16<EPI_BF16><<<dim3(MB, 4), 256, 0, stream>>>(
            E.kv16, wv16 + pW, bv + pB, nullptr, QKV16, 512, 512, 1536, M_PAD, 1024);
        k_attn<<<dim3(B_BATCH, 8), 256, 0, stream>>>(QKV16, offs, num_objs, CTX16);
        k_gemm16<EPI_F32_RESF32><<<dim3(MB, 4), 256, 0, stream>>>(
            CTX16, wo16 + pW, bo + pB, E.qf32, Ob, 512, 512, 512, M_REAL, 0);
        k_ln_bf16out<<<M_PAD, 64, 0, stream>>>(Ob, g1 + pB, be1 + pB, O116);
        k_gemm16<EPI_BF16_RELU><<<dim3(MB, 16), 256, 0, stream>>>(
            O116, w116 + pW1, b1 + pB1, nullptr, H16, 512, 512, 2048, M_PAD, 0);
        k_gemm16<EPI_F32_RESBF16><<<dim3(MB, 4), 256, 0, stream>>>(
            H16, w216 + pW1, b2 + pB, O116, Ob, 2048, 2048, 512, M_PAD, 0);
        if (E.accum) k_ln_f32out<1><<<M_REAL, 64, 0, stream>>>(Ob, g2 + pB, be2 + pB, E.dst);
        else         k_ln_f32out<0><<<M_REAL, 64, 0, stream>>>(Ob, g2 + pB, be2 + pB, E.dst);
    }
}

// Round 3
// 1047.542 us; speedup vs baseline: 7.8587x; 1.6745x over previous
//
#include <hip/hip_runtime.h>
#include <math.h>

#define M_REAL 13320
#define M_PAD  13440          // 105 * 128
#define B_BATCH 240
#define DMODEL 512
#define DINNER 2048
#define LN_EPS 1e-5f

typedef __attribute__((ext_vector_type(8))) short short8;   // bf16x8 frag (4 VGPR)
typedef __attribute__((ext_vector_type(4))) float f32x4;    // MFMA acc

__device__ __forceinline__ ushort f2bf(float f) {
    unsigned u = __float_as_uint(f);
    u += 0x7FFFu + ((u >> 16) & 1u);           // RNE
    return (ushort)(u >> 16);
}
__device__ __forceinline__ float bf2f(ushort h) {
    return __uint_as_float(((unsigned)h) << 16);
}

typedef __attribute__((address_space(3))) unsigned int lds_u32;
typedef __attribute__((address_space(1))) unsigned int glb_u32;
__device__ __forceinline__ void gl_lds16(const ushort* g, ushort* l) {
    __builtin_amdgcn_global_load_lds((glb_u32*)g, (lds_u32*)l, 16, 0, 0);
}

// ---------------- offsets ----------------
__global__ void k_offsets(const int* __restrict__ num_objs, int* __restrict__ offs) {
    if (threadIdx.x == 0) {
        int acc = 0;
        for (int b = 0; b < B_BATCH; ++b) { offs[b] = acc; acc += num_objs[b]; }
    }
}

// ---------------- f32 [M_REAL,512] -> bf16 [M_PAD,512], zero pad rows -------
__global__ __launch_bounds__(256)
void k_cvt_in(const float* __restrict__ src, ushort* __restrict__ dst) {
    int idx = blockIdx.x * 256 + threadIdx.x;   // one thread = 8 elems
    int row = idx >> 6;
    short8 o;
    if (row < M_REAL) {
        const float4* s = (const float4*)src + (size_t)idx * 2;
        float4 a = s[0], b = s[1];
        o[0] = (short)f2bf(a.x); o[1] = (short)f2bf(a.y);
        o[2] = (short)f2bf(a.z); o[3] = (short)f2bf(a.w);
        o[4] = (short)f2bf(b.x); o[5] = (short)f2bf(b.y);
        o[6] = (short)f2bf(b.z); o[7] = (short)f2bf(b.w);
    } else {
        o = (short8)0;
    }
    ((short8*)dst)[idx] = o;
}

// ---------------- weight transpose+cvt: f32 [R,C] -> bf16 [C,R], z-batched --
__global__ __launch_bounds__(256)
void k_wt(const float* __restrict__ src, ushort* __restrict__ dst, int R, int C) {
    __shared__ float t[32][33];
    const float* s = src + (size_t)blockIdx.z * R * C;
    ushort* d = dst + (size_t)blockIdx.z * R * C;
    int tx = threadIdx.x & 31, ty = threadIdx.x >> 5;   // 32 x 8
    int r0 = blockIdx.y * 32, c0 = blockIdx.x * 32;
#pragma unroll
    for (int i = 0; i < 4; ++i)
        t[ty + i * 8][tx] = s[(size_t)(r0 + ty + i * 8) * C + c0 + tx];
    __syncthreads();
#pragma unroll
    for (int i = 0; i < 4; ++i)
        d[(size_t)(c0 + ty + i * 8) * R + r0 + tx] = f2bf(t[tx][ty + i * 8]);
}

// ---------------- bf16 MFMA GEMM (unchanged, verified) -----------------------
enum { EPI_BF16 = 0, EPI_BF16_RELU = 1, EPI_F32_RESF32 = 2, EPI_F32_RESBF16 = 3 };

template<int MODE>
__global__ __launch_bounds__(256)
void k_gemm16(const ushort* __restrict__ A, const ushort* __restrict__ Wt,
              const float* __restrict__ bias, const void* __restrict__ resv,
              void* __restrict__ Cv, int K, int lda, int ldc, int Mreal, int colBase) {
    __shared__ ushort As[128 * 64];
    __shared__ ushort Bs[128 * 64];
    const int tid = threadIdx.x;
    const int row0 = blockIdx.x * 128;
    const int col0 = blockIdx.y * 128;
    const int lane = tid & 63, wid = tid >> 6;
    const int wr = wid >> 1, wc = wid & 1;
    const int fr = lane & 15, fq = lane >> 4;

    int srow[4], scol[4], soff[4];
#pragma unroll
    for (int r = 0; r < 4; ++r) {
        int off = tid * 16 + r * 4096;
        int row = off >> 7;
        int cp  = (off >> 4) & 7;
        soff[r] = off;
        srow[r] = row;
        scol[r] = (cp ^ (row & 7)) * 8;
    }

    f32x4 acc[4][4];
#pragma unroll
    for (int m = 0; m < 4; ++m)
#pragma unroll
        for (int n = 0; n < 4; ++n) acc[m][n] = (f32x4){0.f, 0.f, 0.f, 0.f};

    const int nk = K >> 6;
    for (int kt = 0; kt < nk; ++kt) {
        const int k0 = kt << 6;
#pragma unroll
        for (int r = 0; r < 4; ++r)
            gl_lds16(A + (size_t)(row0 + srow[r]) * lda + k0 + scol[r],
                     (ushort*)((char*)As + soff[r]));
#pragma unroll
        for (int r = 0; r < 4; ++r)
            gl_lds16(Wt + (size_t)(col0 + srow[r]) * K + k0 + scol[r],
                     (ushort*)((char*)Bs + soff[r]));
        __syncthreads();
#pragma unroll
        for (int kk = 0; kk < 2; ++kk) {
            short8 av[4], bv[4];
#pragma unroll
            for (int m = 0; m < 4; ++m) {
                int row = wr * 64 + m * 16 + fr;
                int byte = row * 128 + (((kk * 4 + fq) ^ (row & 7)) << 4);
                av[m] = *(const short8*)((const char*)As + byte);
            }
#pragma unroll
            for (int n = 0; n < 4; ++n) {
                int row = wc * 64 + n * 16 + fr;
                int byte = row * 128 + (((kk * 4 + fq) ^ (row & 7)) << 4);
                bv[n] = *(const short8*)((const char*)Bs + byte);
            }
#pragma unroll
            for (int m = 0; m < 4; ++m)
#pragma unroll
                for (int n = 0; n < 4; ++n)
                    acc[m][n] = __builtin_amdgcn_mfma_f32_16x16x32_bf16(av[m], bv[n], acc[m][n], 0, 0, 0);
        }
        __syncthreads();
    }

#pragma unroll
    for (int m = 0; m < 4; ++m) {
#pragma unroll
        for (int n = 0; n < 4; ++n) {
            int cN = col0 + wc * 64 + n * 16 + fr;
            float bsv = bias[cN];
#pragma unroll
            for (int i = 0; i < 4; ++i) {
                int r = row0 + wr * 64 + m * 16 + fq * 4 + i;
                size_t oidx = (size_t)r * ldc + colBase + cN;
                float v = acc[m][n][i] + bsv;
                if (MODE == EPI_BF16) {
                    ((ushort*)Cv)[oidx] = f2bf(v);
                } else if (MODE == EPI_BF16_RELU) {
                    ((ushort*)Cv)[oidx] = f2bf(fmaxf(v, 0.f));
                } else if (MODE == EPI_F32_RESF32) {
                    if (r < Mreal) v += ((const float*)resv)[oidx];
                    ((float*)Cv)[oidx] = v;
                } else {
                    v += bf2f(((const ushort*)resv)[oidx]);
                    ((float*)Cv)[oidx] = v;
                }
            }
        }
    }
}

// ---------------- MFMA segment attention ------------------------------------
// Block per (b,h), 4 waves. Swapped QK^T -> S^T (q = lane&15), in-register
// softmax, P->bf16 via per-wave LDS strip, ctx^T = mfma(Vt, P).
#define KS_STRIDE 72     // 96 rows x 72 bf16 (16B-aligned rows, 8 uniform bank starts)
#define VT_STRIDE 104    // 64 rows x 104
#define PL_STRIDE 104    // 4*16 rows x 104

__global__ __launch_bounds__(256)
void k_attn_mfma(const ushort* __restrict__ QKV, const int* __restrict__ offs,
                 const int* __restrict__ num_objs, ushort* __restrict__ CTX) {
    __shared__ __attribute__((aligned(16))) ushort Ks[96 * KS_STRIDE];
    __shared__ __attribute__((aligned(16))) ushort Vt[64 * VT_STRIDE];
    __shared__ __attribute__((aligned(16))) ushort Pl[64 * PL_STRIDE];
    const int b = blockIdx.x, h = blockIdx.y;
    const int L = num_objs[b], off = offs[b];
    const int tid = threadIdx.x;
    const int lane = tid & 63, wid = tid >> 6;
    const int fr = lane & 15, fq = lane >> 4;

    // ---- stage K rows + V^T (zero pad rows) ----
#pragma unroll
    for (int pass = 0; pass < 3; ++pass) {
        int j = pass * 32 + (tid >> 3);          // 0..95
        int d0 = (tid & 7) * 8;
        short8 kv = (short8)0, vv = (short8)0;
        if (j < L) {
            size_t base = (size_t)(off + j) * 1536 + h * 64 + d0;
            kv = *(const short8*)(QKV + base + 512);
            vv = *(const short8*)(QKV + base + 1024);
        }
        *(short8*)&Ks[j * KS_STRIDE + d0] = kv;
#pragma unroll
        for (int e = 0; e < 8; ++e) Vt[(d0 + e) * VT_STRIDE + j] = (ushort)vv[e];
    }
    __syncthreads();

    const int nkb = (L + 15) >> 4;               // key blocks (= q blocks)
    const int nkc = (nkb + 1) >> 1;              // 32-key chunks for PV

    for (int qb = wid; qb < 6; qb += 4) {
        if (qb >= nkb) continue;
        const int q0 = qb * 16;
        const int qrow = q0 + fr;
        const int qc = (qrow < L) ? qrow : (L - 1);
        const ushort* qbase = QKV + (size_t)(off + qc) * 1536 + h * 64 + fq * 8;
        short8 qf0 = *(const short8*)qbase;
        short8 qf1 = *(const short8*)(qbase + 32);

        // S^T[k, q] per key block
        f32x4 st[6];
#pragma unroll 6
        for (int kb = 0; kb < nkb; ++kb) {
            short8 a0 = *(const short8*)&Ks[(kb * 16 + fr) * KS_STRIDE + fq * 8];
            short8 a1 = *(const short8*)&Ks[(kb * 16 + fr) * KS_STRIDE + 32 + fq * 8];
            f32x4 acc = (f32x4){0.f, 0.f, 0.f, 0.f};
            acc = __builtin_amdgcn_mfma_f32_16x16x32_bf16(a0, qf0, acc, 0, 0, 0);
            acc = __builtin_amdgcn_mfma_f32_16x16x32_bf16(a1, qf1, acc, 0, 0, 0);
            st[kb] = acc;
        }

        // softmax over k (per q = fr): in-lane + shfl over fq groups
        float m = -1e30f;
#pragma unroll 6
        for (int kb = 0; kb < nkb; ++kb)
#pragma unroll
            for (int i = 0; i < 4; ++i) {
                int k = kb * 16 + fq * 4 + i;
                if (k < L) m = fmaxf(m, st[kb][i] * 0.125f);
            }
        m = fmaxf(m, __shfl_xor(m, 16));
        m = fmaxf(m, __shfl_xor(m, 32));
        float sum = 0.f;
        float pv[6][4];
#pragma unroll
        for (int kb = 0; kb < 6; ++kb)
#pragma unroll
            for (int i = 0; i < 4; ++i) {
                float p = 0.f;
                if (kb < nkb) {
                    int k = kb * 16 + fq * 4 + i;
                    if (k < L) p = __expf(st[kb][i] * 0.125f - m);
                }
                pv[kb][i] = p;
                sum += p;
            }
        sum += __shfl_xor(sum, 16);
        sum += __shfl_xor(sum, 32);
        float inv = 1.f / sum;

        // write P (bf16, zero beyond nkb) into this wave's LDS strip
        ushort* prow = &Pl[(wid * 16 + fr) * PL_STRIDE];
#pragma unroll
        for (int kb = 0; kb < 6; ++kb) {
            unsigned lo = (unsigned)f2bf(pv[kb][0]) | ((unsigned)f2bf(pv[kb][1]) << 16);
            unsigned hi = (unsigned)f2bf(pv[kb][2]) | ((unsigned)f2bf(pv[kb][3]) << 16);
            *(unsigned*)&prow[kb * 16 + fq * 4]     = lo;
            *(unsigned*)&prow[kb * 16 + fq * 4 + 2] = hi;
        }

        // ctx^T[d, q] = sum_kc mfma(Vt-frag, P-frag)
        f32x4 ct[4];
#pragma unroll
        for (int db = 0; db < 4; ++db) ct[db] = (f32x4){0.f, 0.f, 0.f, 0.f};
        const ushort* prd = &Pl[(wid * 16 + fr) * PL_STRIDE];
#pragma unroll 3
        for (int kc = 0; kc < nkc; ++kc) {
            short8 pf = *(const short8*)&prd[kc * 32 + fq * 8];
#pragma unroll
            for (int db = 0; db < 4; ++db) {
                short8 vf = *(const short8*)&Vt[(db * 16 + fr) * VT_STRIDE + kc * 32 + fq * 8];
                ct[db] = __builtin_amdgcn_mfma_f32_16x16x32_bf16(vf, pf, ct[db], 0, 0, 0);
            }
        }

        // write ctx rows q = q0+fr (col of D), d = db*16 + fq*4 + i
        if (qrow < L) {
            ushort* crow = CTX + (size_t)(off + qrow) * 512 + h * 64;
#pragma unroll
            for (int db = 0; db < 4; ++db) {
                ushort4 o;
                o.x = f2bf(ct[db][0] * inv);
                o.y = f2bf(ct[db][1] * inv);
                o.z = f2bf(ct[db][2] * inv);
                o.w = f2bf(ct[db][3] * inv);
                *(ushort4*)&crow[db * 16 + fq * 4] = o;
            }
        }
    }
}

// ---------------- LayerNorm (512 cols, one wave per row) ---------------------
__global__ __launch_bounds__(64)
void k_ln_bf16out(const float* __restrict__ X, const float* __restrict__ g,
                  const float* __restrict__ be, ushort* __restrict__ out) {
    int row = blockIdx.x, lane = threadIdx.x;
    const float4* x4 = (const float4*)(X + (size_t)row * DMODEL);
    float4 v0 = x4[2 * lane], v1 = x4[2 * lane + 1];
    float s = v0.x + v0.y + v0.z + v0.w + v1.x + v1.y + v1.z + v1.w;
    for (int o = 32; o > 0; o >>= 1) s += __shfl_xor(s, o);
    float mean = s * (1.f / 512.f);
    float d0 = v0.x - mean, d1 = v0.y - mean, d2 = v0.z - mean, d3 = v0.w - mean;
    float d4 = v1.x - mean, d5 = v1.y - mean, d6 = v1.z - mean, d7 = v1.w - mean;
    float vs = d0*d0 + d1*d1 + d2*d2 + d3*d3 + d4*d4 + d5*d5 + d6*d6 + d7*d7;
    for (int o = 32; o > 0; o >>= 1) vs += __shfl_xor(vs, o);
    float rstd = rsqrtf(vs * (1.f / 512.f) + LN_EPS);
    const float4* g4 = (const float4*)g;
    const float4* b4 = (const float4*)be;
    float4 ga = g4[2 * lane], gb = g4[2 * lane + 1];
    float4 ba = b4[2 * lane], bb = b4[2 * lane + 1];
    short8 o8;
    o8[0] = (short)f2bf(d0 * rstd * ga.x + ba.x);
    o8[1] = (short)f2bf(d1 * rstd * ga.y + ba.y);
    o8[2] = (short)f2bf(d2 * rstd * ga.z + ba.z);
    o8[3] = (short)f2bf(d3 * rstd * ga.w + ba.w);
    o8[4] = (short)f2bf(d4 * rstd * gb.x + bb.x);
    o8[5] = (short)f2bf(d5 * rstd * gb.y + bb.y);
    o8[6] = (short)f2bf(d6 * rstd * gb.z + bb.z);
    o8[7] = (short)f2bf(d7 * rstd * gb.w + bb.w);
    ((short8*)(out + (size_t)row * DMODEL))[lane] = o8;
}

template<int ACCUM>
__global__ __launch_bounds__(64)
void k_ln_f32out(const float* __restrict__ X, const float* __restrict__ g,
                 const float* __restrict__ be, float* __restrict__ out) {
    int row = blockIdx.x, lane = threadIdx.x;
    const float4* x4 = (const float4*)(X + (size_t)row * DMODEL);
    float4 v0 = x4[2 * lane], v1 = x4[2 * lane + 1];
    float s = v0.x + v0.y + v0.z + v0.w + v1.x + v1.y + v1.z + v1.w;
    for (int o = 32; o > 0; o >>= 1) s += __shfl_xor(s, o);
    float mean = s * (1.f / 512.f);
    float d0 = v0.x - mean, d1 = v0.y - mean, d2 = v0.z - mean, d3 = v0.w - mean;
    float d4 = v1.x - mean, d5 = v1.y - mean, d6 = v1.z - mean, d7 = v1.w - mean;
    float vs = d0*d0 + d1*d1 + d2*d2 + d3*d3 + d4*d4 + d5*d5 + d6*d6 + d7*d7;
    for (int o = 32; o > 0; o >>= 1) vs += __shfl_xor(vs, o);
    float rstd = rsqrtf(vs * (1.f / 512.f) + LN_EPS);
    const float4* g4 = (const float4*)g;
    const float4* b4 = (const float4*)be;
    float4 ga = g4[2 * lane], gb = g4[2 * lane + 1];
    float4 ba = b4[2 * lane], bb = b4[2 * lane + 1];
    float4 o0, o1;
    o0.x = d0 * rstd * ga.x + ba.x;  o0.y = d1 * rstd * ga.y + ba.y;
    o0.z = d2 * rstd * ga.z + ba.z;  o0.w = d3 * rstd * ga.w + ba.w;
    o1.x = d4 * rstd * gb.x + bb.x;  o1.y = d5 * rstd * gb.y + bb.y;
    o1.z = d6 * rstd * gb.z + bb.z;  o1.w = d7 * rstd * gb.w + bb.w;
    float4* out4 = (float4*)(out + (size_t)row * DMODEL);
    if (ACCUM) {
        float4 e0 = out4[2 * lane], e1 = out4[2 * lane + 1];
        o0.x += e0.x; o0.y += e0.y; o0.z += e0.z; o0.w += e0.w;
        o1.x += e1.x; o1.y += e1.y; o1.z += e1.z; o1.w += e1.w;
    }
    out4[2 * lane] = o0;
    out4[2 * lane + 1] = o1;
}

// ---------------- driver ------------------------------------------------------
extern "C" void kernel_launch(void* const* d_in, const int* in_sizes, int n_in,
                              void* d_out, int out_size, void* d_ws, size_t ws_size,
                              hipStream_t stream) {
    const float* vis = (const float*)d_in[0];
    const float* txt = (const float*)d_in[1];
    const float* Wq  = (const float*)d_in[2];
    const float* bq  = (const float*)d_in[3];
    const float* Wk  = (const float*)d_in[4];
    const float* bk  = (const float*)d_in[5];
    const float* Wv  = (const float*)d_in[6];
    const float* bv  = (const float*)d_in[7];
    const float* Wo  = (const float*)d_in[8];
    const float* bo  = (const float*)d_in[9];
    const float* g1  = (const float*)d_in[10];
    const float* be1 = (const float*)d_in[11];
    const float* W1  = (const float*)d_in[12];
    const float* b1  = (const float*)d_in[13];
    const float* W2  = (const float*)d_in[14];
    const float* b2  = (const float*)d_in[15];
    const float* g2  = (const float*)d_in[16];
    const float* be2 = (const float*)d_in[17];
    const int* num_objs = (const int*)d_in[18];

    char* p = (char*)d_ws;
    ushort* vis16 = (ushort*)p;               p += (size_t)M_PAD * 512 * 2;
    ushort* txt16 = (ushort*)p;               p += (size_t)M_PAD * 512 * 2;
    ushort* wq16  = (ushort*)p;               p += (size_t)4 * 512 * 512 * 2;
    ushort* wk16  = (ushort*)p;               p += (size_t)4 * 512 * 512 * 2;
    ushort* wv16  = (ushort*)p;               p += (size_t)4 * 512 * 512 * 2;
    ushort* wo16  = (ushort*)p;               p += (size_t)4 * 512 * 512 * 2;
    ushort* w116  = (ushort*)p;               p += (size_t)4 * 512 * 2048 * 2;
    ushort* w216  = (ushort*)p;               p += (size_t)4 * 512 * 2048 * 2;
    ushort* QKV16 = (ushort*)p;               p += (size_t)M_PAD * 1536 * 2;
    ushort* CTX16 = (ushort*)p;               p += (size_t)M_PAD * 512 * 2;
    ushort* O116  = (ushort*)p;               p += (size_t)M_PAD * 512 * 2;
    ushort* H16   = (ushort*)p;               p += (size_t)M_PAD * 2048 * 2;
    float*  Ob    = (float*)p;                p += (size_t)M_PAD * 512 * 4;
    int*    offs  = (int*)p;                  p += 1024;

    float* outv = (float*)d_out;
    float* outt = outv + (size_t)M_REAL * DMODEL;

    k_offsets<<<1, 64, 0, stream>>>(num_objs, offs);
    k_cvt_in<<<3360, 256, 0, stream>>>(vis, vis16);
    k_cvt_in<<<3360, 256, 0, stream>>>(txt, txt16);
    k_wt<<<dim3(16, 16, 4), 256, 0, stream>>>(Wq, wq16, 512, 512);
    k_wt<<<dim3(16, 16, 4), 256, 0, stream>>>(Wk, wk16, 512, 512);
    k_wt<<<dim3(16, 16, 4), 256, 0, stream>>>(Wv, wv16, 512, 512);
    k_wt<<<dim3(16, 16, 4), 256, 0, stream>>>(Wo, wo16, 512, 512);
    k_wt<<<dim3(64, 16, 4), 256, 0, stream>>>(W1, w116, 512, 2048);
    k_wt<<<dim3(16, 64, 4), 256, 0, stream>>>(W2, w216, 2048, 512);

    struct Enc { const ushort* q16; const ushort* kv16; const float* qf32; int p; float* dst; int accum; };
    Enc encs[4] = {
        { txt16, txt16, txt, 1, outt, 0 },   // tsa
        { txt16, vis16, txt, 3, outt, 1 },   // tca
        { vis16, vis16, vis, 0, outv, 0 },   // vsa
        { vis16, txt16, vis, 2, outv, 1 },   // vca
    };

    const int MB = M_PAD / 128;   // 105
    for (int e = 0; e < 4; ++e) {
        const Enc& E = encs[e];
        size_t pW  = (size_t)E.p * 512 * 512;
        size_t pB  = (size_t)E.p * 512;
        size_t pW1 = (size_t)E.p * 512 * 2048;
        size_t pB1 = (size_t)E.p * 2048;

        k_gemm16<EPI_BF16><<<dim3(MB, 4), 256, 0, stream>>>(
            E.q16,  wq16 + pW, bq + pB, nullptr, QKV16, 512, 512, 1536, M_PAD, 0);
        k_gemm16<EPI_BF16><<<dim3(MB, 4), 256, 0, stream>>>(
            E.kv16, wk16 + pW, bk + pB, nullptr, QKV16, 512, 512, 1536, M_PAD, 512);
        k_gemm16<EPI_BF16><<<dim3(MB, 4), 256, 0, stream>>>(
            E.kv16, wv16 + pW, bv + pB, nullptr, QKV16, 512, 512, 1536, M_PAD, 1024);
        k_attn_mfma<<<dim3(B_BATCH, 8), 256, 0, stream>>>(QKV16, offs, num_objs, CTX16);
        k_gemm16<EPI_F32_RESF32><<<dim3(MB, 4), 256, 0, stream>>>(
            CTX16, wo16 + pW, bo + pB, E.qf32, Ob, 512, 512, 512, M_REAL, 0);
        k_ln_bf16out<<<M_PAD, 64, 0, stream>>>(Ob, g1 + pB, be1 + pB, O116);
        k_gemm16<EPI_BF16_RELU><<<dim3(MB, 16), 256, 0, stream>>>(
            O116, w116 + pW1, b1 + pB1, nullptr, H16, 512, 512, 2048, M_PAD, 0);
        k_gemm16<EPI_F32_RESBF16><<<dim3(MB, 4), 256, 0, stream>>>(
            H16, w216 + pW1, b2 + pB, O116, Ob, 2048, 2048, 512, M_PAD, 0);
        if (E.accum) k_ln_f32out<1><<<M_REAL, 64, 0, stream>>>(Ob, g2 + pB, be2 + pB, E.dst);
        else         k_ln_f32out<0><<<M_REAL, 64, 0, stream>>>(Ob, g2 + pB, be2 + pB, E.dst);
    }
}

// Round 5
// 873.116 us; speedup vs baseline: 9.4286x; 1.1998x over previous
//
#include <hip/hip_runtime.h>
#include <math.h>

#define M_REAL 13320
#define M_PAD  13440          // 105 * 128
#define B_BATCH 240
#define LN_EPS 1e-5f

#define MS512  ((size_t)M_PAD * 512)
#define MS2048 ((size_t)M_PAD * 2048)

typedef __attribute__((ext_vector_type(8))) short short8;   // bf16x8 frag (4 VGPR)
typedef __attribute__((ext_vector_type(4))) float f32x4;    // MFMA acc

__device__ __forceinline__ ushort f2bf(float f) {
    unsigned u = __float_as_uint(f);
    u += 0x7FFFu + ((u >> 16) & 1u);           // RNE
    return (ushort)(u >> 16);
}
__device__ __forceinline__ float bf2f(ushort h) {
    return __uint_as_float(((unsigned)h) << 16);
}
__device__ __forceinline__ int sel4(int4 v, int z) {
    return z == 0 ? v.x : z == 1 ? v.y : z == 2 ? v.z : v.w;
}

typedef __attribute__((address_space(3))) unsigned int lds_u32;
typedef __attribute__((address_space(1))) unsigned int glb_u32;
__device__ __forceinline__ void gl_lds16(const ushort* g, ushort* l) {
    __builtin_amdgcn_global_load_lds((glb_u32*)g, (lds_u32*)l, 16, 0, 0);
}

// ---------------- offsets ----------------
__global__ void k_offsets(const int* __restrict__ num_objs, int* __restrict__ offs) {
    if (threadIdx.x == 0) {
        int acc = 0;
        for (int b = 0; b < B_BATCH; ++b) { offs[b] = acc; acc += num_objs[b]; }
    }
}

// ---------------- f32 [M_REAL,512] -> bf16 [M_PAD,512], zero pad rows -------
__global__ __launch_bounds__(256)
void k_cvt_in(const float* __restrict__ src, ushort* __restrict__ dst) {
    int idx = blockIdx.x * 256 + threadIdx.x;   // one thread = 8 elems
    int row = idx >> 6;
    short8 o;
    if (row < M_REAL) {
        const float4* s = (const float4*)src + (size_t)idx * 2;
        float4 a = s[0], b = s[1];
        o[0] = (short)f2bf(a.x); o[1] = (short)f2bf(a.y);
        o[2] = (short)f2bf(a.z); o[3] = (short)f2bf(a.w);
        o[4] = (short)f2bf(b.x); o[5] = (short)f2bf(b.y);
        o[6] = (short)f2bf(b.z); o[7] = (short)f2bf(b.w);
    } else {
        o = (short8)0;
    }
    ((short8*)dst)[idx] = o;
}

// ---------------- bias concat: bqkv[e][1536] = cat(bq,bk,bv) -----------------
__global__ void k_cat_bias(const float* __restrict__ bq, const float* __restrict__ bk,
                           const float* __restrict__ bv, float* __restrict__ out) {
    int idx = blockIdx.x * 256 + threadIdx.x;
    if (idx >= 4 * 1536) return;
    int e = idx / 1536, c = idx - e * 1536;
    float v = (c < 512) ? bq[e * 512 + c] : (c < 1024) ? bk[e * 512 + c - 512]
                                                       : bv[e * 512 + c - 1024];
    out[idx] = v;
}

// ---------------- weight transpose+cvt: f32 [R,C] -> bf16 [C,R] --------------
__global__ __launch_bounds__(256)
void k_wt(const float* __restrict__ src, ushort* __restrict__ dst, int R, int C,
          size_t dstStride, size_t dstOff) {
    __shared__ float t[32][33];
    const float* s = src + (size_t)blockIdx.z * R * C;
    ushort* d = dst + (size_t)blockIdx.z * dstStride + dstOff;
    int tx = threadIdx.x & 31, ty = threadIdx.x >> 5;   // 32 x 8
    int r0 = blockIdx.y * 32, c0 = blockIdx.x * 32;
#pragma unroll
    for (int i = 0; i < 4; ++i)
        t[ty + i * 8][tx] = s[(size_t)(r0 + ty + i * 8) * C + c0 + tx];
    __syncthreads();
#pragma unroll
    for (int i = 0; i < 4; ++i)
        d[(size_t)(c0 + ty + i * 8) * R + r0 + tx] = f2bf(t[tx][ty + i * 8]);
}

// ---------------- bf16 MFMA GEMM (verified inner loop) -----------------------
// Generalized: z-batched (strides + per-z weight index), A selected per
// column-block (fused QKV), XCD-chunked work remap for L2 locality.
enum { EPI_BF16 = 0, EPI_BF16_RELU = 1, EPI_F32_RESF32 = 2, EPI_F32_RESBF16 = 3 };

template<int MODE>
__global__ __launch_bounds__(256)
void k_gemm16(const ushort* __restrict__ A, const ushort* __restrict__ A2, int bySplit,
              size_t zA, int lda,
              const ushort* __restrict__ Wb, size_t wSize, int4 widx, int K,
              const float* __restrict__ biasB, int biasStride,
              const void* __restrict__ resv, const void* __restrict__ resv2,
              int resSplit, size_t zRes,
              void* __restrict__ Cv, size_t zC, int ldc, int Mreal) {
    __shared__ ushort As[128 * 64];
    __shared__ ushort Bs[128 * 64];
    const int tid = threadIdx.x;

    // ---- XCD-chunked remap: dispatch ordinal d -> contiguous work per XCD ----
    const int NX = gridDim.x, NY = gridDim.y;
    const int NB = NX * NY * (int)gridDim.z;
    int d = blockIdx.x + NX * (blockIdx.y + NY * blockIdx.z);
    int qq = NB >> 3, rr = NB & 7;
    int xcd = d & 7, idx = d >> 3;
    int work = (xcd < rr ? xcd * (qq + 1) : rr * (qq + 1) + (xcd - rr) * qq) + idx;
    const int z = work / (NX * NY);
    int rem = work - z * (NX * NY);
    const int panel = rem / NY;            // row-panel index (col-fastest within panel)
    const int colb = rem - panel * NY;
    const int row0 = panel * 128;
    const int col0 = colb * 128;

    const ushort* Ause = ((colb < bySplit) ? A : A2) + (size_t)z * zA;
    const ushort* Wt = Wb + (size_t)sel4(widx, z) * wSize;
    const float* bias = biasB + (size_t)sel4(widx, z) * biasStride;
    const int zi = (z < resSplit) ? z : z - resSplit;
    const float*  resF = (const float*)((z < resSplit) ? resv : resv2) + (size_t)zi * zRes;
    const ushort* resH = (const ushort*)((z < resSplit) ? resv : resv2) + (size_t)zi * zRes;
    ushort* C16 = (ushort*)Cv + (size_t)z * zC;
    float*  C32 = (float*)Cv + (size_t)z * zC;

    const int lane = tid & 63, wid = tid >> 6;
    const int wr = wid >> 1, wc = wid & 1;
    const int fr = lane & 15, fq = lane >> 4;

    int srow[4], scol[4], soff[4];
#pragma unroll
    for (int r = 0; r < 4; ++r) {
        int off = tid * 16 + r * 4096;
        int row = off >> 7;
        int cp  = (off >> 4) & 7;
        soff[r] = off;
        srow[r] = row;
        scol[r] = (cp ^ (row & 7)) * 8;
    }

    f32x4 acc[4][4];
#pragma unroll
    for (int m = 0; m < 4; ++m)
#pragma unroll
        for (int n = 0; n < 4; ++n) acc[m][n] = (f32x4){0.f, 0.f, 0.f, 0.f};

    const int nk = K >> 6;
    for (int kt = 0; kt < nk; ++kt) {
        const int k0 = kt << 6;
#pragma unroll
        for (int r = 0; r < 4; ++r)
            gl_lds16(Ause + (size_t)(row0 + srow[r]) * lda + k0 + scol[r],
                     (ushort*)((char*)As + soff[r]));
#pragma unroll
        for (int r = 0; r < 4; ++r)
            gl_lds16(Wt + (size_t)(col0 + srow[r]) * K + k0 + scol[r],
                     (ushort*)((char*)Bs + soff[r]));
        __syncthreads();
#pragma unroll
        for (int kk = 0; kk < 2; ++kk) {
            short8 av[4], bv[4];
#pragma unroll
            for (int m = 0; m < 4; ++m) {
                int row = wr * 64 + m * 16 + fr;
                int byte = row * 128 + (((kk * 4 + fq) ^ (row & 7)) << 4);
                av[m] = *(const short8*)((const char*)As + byte);
            }
#pragma unroll
            for (int n = 0; n < 4; ++n) {
                int row = wc * 64 + n * 16 + fr;
                int byte = row * 128 + (((kk * 4 + fq) ^ (row & 7)) << 4);
                bv[n] = *(const short8*)((const char*)Bs + byte);
            }
#pragma unroll
            for (int m = 0; m < 4; ++m)
#pragma unroll
                for (int n = 0; n < 4; ++n)
                    acc[m][n] = __builtin_amdgcn_mfma_f32_16x16x32_bf16(av[m], bv[n], acc[m][n], 0, 0, 0);
        }
        __syncthreads();
    }

    // epilogue: C/D layout col=lane&15, row=(lane>>4)*4+i
#pragma unroll
    for (int m = 0; m < 4; ++m) {
#pragma unroll
        for (int n = 0; n < 4; ++n) {
            int cN = col0 + wc * 64 + n * 16 + fr;
            float bsv = bias[cN];
#pragma unroll
            for (int i = 0; i < 4; ++i) {
                int r = row0 + wr * 64 + m * 16 + fq * 4 + i;
                size_t oidx = (size_t)r * ldc + cN;
                float v = acc[m][n][i] + bsv;
                if (MODE == EPI_BF16) {
                    C16[oidx] = f2bf(v);
                } else if (MODE == EPI_BF16_RELU) {
                    C16[oidx] = f2bf(fmaxf(v, 0.f));
                } else if (MODE == EPI_F32_RESF32) {
                    if (r < Mreal) v += resF[oidx];
                    C32[oidx] = v;
                } else {
                    v += bf2f(resH[oidx]);
                    C32[oidx] = v;
                }
            }
        }
    }
}

// ---------------- MFMA segment attention (verified) --------------------------
#define KS_STRIDE 72
#define VT_STRIDE 104
#define PL_STRIDE 104

__global__ __launch_bounds__(256)
void k_attn_mfma(const ushort* __restrict__ QKV, const int* __restrict__ offs,
                 const int* __restrict__ num_objs, ushort* __restrict__ CTX) {
    __shared__ __attribute__((aligned(16))) ushort Ks[96 * KS_STRIDE];
    __shared__ __attribute__((aligned(16))) ushort Vt[64 * VT_STRIDE];
    __shared__ __attribute__((aligned(16))) ushort Pl[64 * PL_STRIDE];
    const int b = blockIdx.x, h = blockIdx.y;
    const int L = num_objs[b], off = offs[b];
    const int tid = threadIdx.x;
    const int lane = tid & 63, wid = tid >> 6;
    const int fr = lane & 15, fq = lane >> 4;

#pragma unroll
    for (int pass = 0; pass < 3; ++pass) {
        int j = pass * 32 + (tid >> 3);
        int d0 = (tid & 7) * 8;
        short8 kv = (short8)0, vv = (short8)0;
        if (j < L) {
            size_t base = (size_t)(off + j) * 1536 + h * 64 + d0;
            kv = *(const short8*)(QKV + base + 512);
            vv = *(const short8*)(QKV + base + 1024);
        }
        *(short8*)&Ks[j * KS_STRIDE + d0] = kv;
#pragma unroll
        for (int e = 0; e < 8; ++e) Vt[(d0 + e) * VT_STRIDE + j] = (ushort)vv[e];
    }
    __syncthreads();

    const int nkb = (L + 15) >> 4;
    const int nkc = (nkb + 1) >> 1;

    for (int qb = wid; qb < 6; qb += 4) {
        if (qb >= nkb) continue;
        const int q0 = qb * 16;
        const int qrow = q0 + fr;
        const int qc = (qrow < L) ? qrow : (L - 1);
        const ushort* qbase = QKV + (size_t)(off + qc) * 1536 + h * 64 + fq * 8;
        short8 qf0 = *(const short8*)qbase;
        short8 qf1 = *(const short8*)(qbase + 32);

        f32x4 st[6];
#pragma unroll 6
        for (int kb = 0; kb < nkb; ++kb) {
            short8 a0 = *(const short8*)&Ks[(kb * 16 + fr) * KS_STRIDE + fq * 8];
            short8 a1 = *(const short8*)&Ks[(kb * 16 + fr) * KS_STRIDE + 32 + fq * 8];
            f32x4 acc = (f32x4){0.f, 0.f, 0.f, 0.f};
            acc = __builtin_amdgcn_mfma_f32_16x16x32_bf16(a0, qf0, acc, 0, 0, 0);
            acc = __builtin_amdgcn_mfma_f32_16x16x32_bf16(a1, qf1, acc, 0, 0, 0);
            st[kb] = acc;
        }

        float m = -1e30f;
#pragma unroll 6
        for (int kb = 0; kb < nkb; ++kb)
#pragma unroll
            for (int i = 0; i < 4; ++i) {
                int k = kb * 16 + fq * 4 + i;
                if (k < L) m = fmaxf(m, st[kb][i] * 0.125f);
            }
        m = fmaxf(m, __shfl_xor(m, 16));
        m = fmaxf(m, __shfl_xor(m, 32));
        float sum = 0.f;
        float pv[6][4];
#pragma unroll
        for (int kb = 0; kb < 6; ++kb)
#pragma unroll
            for (int i = 0; i < 4; ++i) {
                float p = 0.f;
                if (kb < nkb) {
                    int k = kb * 16 + fq * 4 + i;
                    if (k < L) p = __expf(st[kb][i] * 0.125f - m);
                }
                pv[kb][i] = p;
                sum += p;
            }
        sum += __shfl_xor(sum, 16);
        sum += __shfl_xor(sum, 32);
        float inv = 1.f / sum;

        ushort* prow = &Pl[(wid * 16 + fr) * PL_STRIDE];
#pragma unroll
        for (int kb = 0; kb < 6; ++kb) {
            unsigned lo = (unsigned)f2bf(pv[kb][0]) | ((unsigned)f2bf(pv[kb][1]) << 16);
            unsigned hi = (unsigned)f2bf(pv[kb][2]) | ((unsigned)f2bf(pv[kb][3]) << 16);
            *(unsigned*)&prow[kb * 16 + fq * 4]     = lo;
            *(unsigned*)&prow[kb * 16 + fq * 4 + 2] = hi;
        }

        f32x4 ct[4];
#pragma unroll
        for (int db = 0; db < 4; ++db) ct[db] = (f32x4){0.f, 0.f, 0.f, 0.f};
        const ushort* prd = &Pl[(wid * 16 + fr) * PL_STRIDE];
#pragma unroll 3
        for (int kc = 0; kc < nkc; ++kc) {
            short8 pf = *(const short8*)&prd[kc * 32 + fq * 8];
#pragma unroll
            for (int db = 0; db < 4; ++db) {
                short8 vf = *(const short8*)&Vt[(db * 16 + fr) * VT_STRIDE + kc * 32 + fq * 8];
                ct[db] = __builtin_amdgcn_mfma_f32_16x16x32_bf16(vf, pf, ct[db], 0, 0, 0);
            }
        }

        if (qrow < L) {
            ushort* crow = CTX + (size_t)(off + qrow) * 512 + h * 64;
#pragma unroll
            for (int db = 0; db < 4; ++db) {
                ushort4 o;
                o.x = f2bf(ct[db][0] * inv);
                o.y = f2bf(ct[db][1] * inv);
                o.z = f2bf(ct[db][2] * inv);
                o.w = f2bf(ct[db][3] * inv);
                *(ushort4*)&crow[db * 16 + fq * 4] = o;
            }
        }
    }
}

// ---------------- LayerNorm helpers (one wave per row) -----------------------
__device__ __forceinline__ void ln_row8(const float* __restrict__ X, const float* __restrict__ g,
                                        const float* __restrict__ be, int lane, float* o) {
    const float4* x4 = (const float4*)X;
    float4 v0 = x4[2 * lane], v1 = x4[2 * lane + 1];
    float s = v0.x + v0.y + v0.z + v0.w + v1.x + v1.y + v1.z + v1.w;
    for (int t = 32; t > 0; t >>= 1) s += __shfl_xor(s, t);
    float mean = s * (1.f / 512.f);
    float dd[8] = {v0.x - mean, v0.y - mean, v0.z - mean, v0.w - mean,
                   v1.x - mean, v1.y - mean, v1.z - mean, v1.w - mean};
    float vs = 0.f;
#pragma unroll
    for (int i = 0; i < 8; ++i) vs += dd[i] * dd[i];
    for (int t = 32; t > 0; t >>= 1) vs += __shfl_xor(vs, t);
    float rstd = rsqrtf(vs * (1.f / 512.f) + LN_EPS);
    const float4* g4 = (const float4*)g;
    const float4* b4 = (const float4*)be;
    float4 ga = g4[2 * lane], gb = g4[2 * lane + 1];
    float4 ba = b4[2 * lane], bb = b4[2 * lane + 1];
    o[0] = dd[0] * rstd * ga.x + ba.x;  o[1] = dd[1] * rstd * ga.y + ba.y;
    o[2] = dd[2] * rstd * ga.z + ba.z;  o[3] = dd[3] * rstd * ga.w + ba.w;
    o[4] = dd[4] * rstd * gb.x + bb.x;  o[5] = dd[5] * rstd * gb.y + bb.y;
    o[6] = dd[6] * rstd * gb.z + bb.z;  o[7] = dd[7] * rstd * gb.w + bb.w;
}

// LN1 batched over z encoders (z=blockIdx.y), bf16 out. 4 rows per block.
__global__ __launch_bounds__(256)
void k_ln1(const float* __restrict__ Xb, const float* __restrict__ gB,
           const float* __restrict__ beB, ushort* __restrict__ outB, int4 widx) {
    int e = blockIdx.y;
    int row = blockIdx.x * 4 + (threadIdx.x >> 6);
    int lane = threadIdx.x & 63;
    int pi = sel4(widx, e);
    float o[8];
    ln_row8(Xb + (size_t)e * MS512 + (size_t)row * 512, gB + pi * 512, beB + pi * 512, lane, o);
    short8 o8;
#pragma unroll
    for (int i = 0; i < 8; ++i) o8[i] = (short)f2bf(o[i]);
    ((short8*)(outB + (size_t)e * MS512 + (size_t)row * 512))[lane] = o8;
}

// LN2 + pair sum: dst = LN(Ob2[0]; pA) + LN(Ob2[1]; pB)
__global__ __launch_bounds__(256)
void k_ln2pair(const float* __restrict__ Ob2, const float* __restrict__ gB,
               const float* __restrict__ beB, float* __restrict__ dst,
               int pA, int pB) {
    int row = blockIdx.x * 4 + (threadIdx.x >> 6);
    int lane = threadIdx.x & 63;
    float oA[8], oB[8];
    ln_row8(Ob2 + (size_t)row * 512,         gB + pA * 512, beB + pA * 512, lane, oA);
    ln_row8(Ob2 + MS512 + (size_t)row * 512, gB + pB * 512, beB + pB * 512, lane, oB);
    if (row < M_REAL) {
        float* drow = dst + (size_t)row * 512;
        float4 s0, s1;
        s0.x = oA[0] + oB[0]; s0.y = oA[1] + oB[1]; s0.z = oA[2] + oB[2]; s0.w = oA[3] + oB[3];
        s1.x = oA[4] + oB[4]; s1.y = oA[5] + oB[5]; s1.z = oA[6] + oB[6]; s1.w = oA[7] + oB[7];
        ((float4*)drow)[2 * lane] = s0;
        ((float4*)drow)[2 * lane + 1] = s1;
    }
}

// ---------------- driver ------------------------------------------------------
extern "C" void kernel_launch(void* const* d_in, const int* in_sizes, int n_in,
                              void* d_out, int out_size, void* d_ws, size_t ws_size,
                              hipStream_t stream) {
    const float* vis = (const float*)d_in[0];
    const float* txt = (const float*)d_in[1];
    const float* Wq  = (const float*)d_in[2];
    const float* bq  = (const float*)d_in[3];
    const float* Wk  = (const float*)d_in[4];
    const float* bk  = (const float*)d_in[5];
    const float* Wv  = (const float*)d_in[6];
    const float* bv  = (const float*)d_in[7];
    const float* Wo  = (const float*)d_in[8];
    const float* bo  = (const float*)d_in[9];
    const float* g1  = (const float*)d_in[10];
    const float* be1 = (const float*)d_in[11];
    const float* W1  = (const float*)d_in[12];
    const float* b1  = (const float*)d_in[13];
    const float* W2  = (const float*)d_in[14];
    const float* b2  = (const float*)d_in[15];
    const float* g2  = (const float*)d_in[16];
    const float* be2 = (const float*)d_in[17];
    const int* num_objs = (const int*)d_in[18];

    // ---- workspace (aliased unions): 190.3 MB total (< proven-good 203 MB) --
    char* p = (char*)d_ws;
    ushort* QKV16  = (ushort*)p;               // U1: [M_PAD][1536] bf16 (QKV phase)
    ushort* H16    = (ushort*)p;               // U1: [M_PAD][2048] bf16 (FFN phase)
    p += (size_t)M_PAD * 2048 * 2;             // 55.05 MB
    ushort* CTX2   = (ushort*)p;               // U2: [2][M_PAD][512] bf16 (attn out)
    ushort* O116_2 = (ushort*)p;               // U2 alias: LN1 out (CTX dead after Wo)
    p += (size_t)2 * MS512 * 2;                // 27.5 MB
    float*  Ob2    = (float*)p;                // U3: [2][M_PAD][512] f32 (Wo out / FFN2 out)
    p += (size_t)2 * MS512 * 4;                // 55.05 MB
    ushort* vis16  = (ushort*)p;  p += MS512 * 2;
    ushort* txt16  = (ushort*)p;  p += MS512 * 2;
    ushort* wqkv16 = (ushort*)p;  p += (size_t)4 * 1536 * 512 * 2;
    ushort* wo16   = (ushort*)p;  p += (size_t)4 * 512 * 512 * 2;
    ushort* w116   = (ushort*)p;  p += (size_t)4 * 2048 * 512 * 2;
    ushort* w216   = (ushort*)p;  p += (size_t)4 * 512 * 2048 * 2;
    float*  bqkv   = (float*)p;   p += (size_t)4 * 1536 * 4;
    int*    offs   = (int*)p;     p += 1024;

    float* outv = (float*)d_out;
    float* outt = outv + (size_t)M_REAL * 512;

    k_offsets<<<1, 64, 0, stream>>>(num_objs, offs);
    k_cvt_in<<<3360, 256, 0, stream>>>(vis, vis16);
    k_cvt_in<<<3360, 256, 0, stream>>>(txt, txt16);
    k_cat_bias<<<24, 256, 0, stream>>>(bq, bk, bv, bqkv);
    // wqkv[e] = [1536][512]: rows 0-511 Wq^T, 512-1023 Wk^T, 1024-1535 Wv^T
    k_wt<<<dim3(16, 16, 4), 256, 0, stream>>>(Wq, wqkv16, 512, 512, (size_t)1536 * 512, 0);
    k_wt<<<dim3(16, 16, 4), 256, 0, stream>>>(Wk, wqkv16, 512, 512, (size_t)1536 * 512, (size_t)512 * 512);
    k_wt<<<dim3(16, 16, 4), 256, 0, stream>>>(Wv, wqkv16, 512, 512, (size_t)1536 * 512, (size_t)1024 * 512);
    k_wt<<<dim3(16, 16, 4), 256, 0, stream>>>(Wo, wo16, 512, 512, (size_t)512 * 512, 0);
    k_wt<<<dim3(64, 16, 4), 256, 0, stream>>>(W1, w116, 512, 2048, (size_t)2048 * 512, 0);
    k_wt<<<dim3(16, 64, 4), 256, 0, stream>>>(W2, w216, 2048, 512, (size_t)512 * 2048, 0);

    // e order: 0=tsa(txt,txt,p1) 1=tca(txt,vis,p3) 2=vsa(vis,vis,p0) 3=vca(vis,txt,p2)
    const int perm[4] = {1, 3, 0, 2};
    const ushort* qsrc[4]  = {txt16, txt16, vis16, vis16};
    const ushort* kvsrc[4] = {txt16, vis16, vis16, txt16};

    for (int pr = 0; pr < 2; ++pr) {
        // ---- QKV (fused N=1536) + attention, per encoder of the pair ----
        for (int z = 0; z < 2; ++z) {
            int e = 2 * pr + z;
            int4 wz = make_int4(perm[e], perm[e], perm[e], perm[e]);
            k_gemm16<EPI_BF16><<<dim3(105, 12, 1), 256, 0, stream>>>(
                qsrc[e], kvsrc[e], 4, 0, 512,
                wqkv16, (size_t)1536 * 512, wz, 512,
                bqkv, 1536,
                nullptr, nullptr, 8, 0,
                QKV16, 0, 1536, M_PAD);
            k_attn_mfma<<<dim3(B_BATCH, 8), 256, 0, stream>>>(
                QKV16, offs, num_objs, CTX2 + (size_t)z * MS512);
        }
        // ---- Wo (z=2): Ob2[z] = CTX2[z]@Wo + bo + q_in (f32) ----
        int4 wzp = make_int4(perm[2 * pr], perm[2 * pr + 1], 0, 0);
        const float* resq = pr ? vis : txt;
        k_gemm16<EPI_F32_RESF32><<<dim3(105, 4, 2), 256, 0, stream>>>(
            CTX2, CTX2, 99, MS512, 512,
            wo16, (size_t)512 * 512, wzp, 512,
            bo, 512,
            resq, resq, 2, 0,
            Ob2, MS512, 512, M_REAL);
        // ---- LN1 (z=2) -> bf16 (overwrites CTX alias) ----
        k_ln1<<<dim3(3360, 2), 256, 0, stream>>>(Ob2, g1, be1, O116_2, wzp);
        // ---- FFN per encoder (H16 single-buffer) ----
        for (int z = 0; z < 2; ++z) {
            int e = 2 * pr + z;
            int4 wz = make_int4(perm[e], perm[e], perm[e], perm[e]);
            k_gemm16<EPI_BF16_RELU><<<dim3(105, 16, 1), 256, 0, stream>>>(
                O116_2 + (size_t)z * MS512, O116_2, 99, 0, 512,
                w116, (size_t)2048 * 512, wz, 512,
                b1, 2048,
                nullptr, nullptr, 8, 0,
                H16, 0, 2048, M_PAD);
            k_gemm16<EPI_F32_RESBF16><<<dim3(105, 4, 1), 256, 0, stream>>>(
                H16, H16, 99, 0, 2048,
                w216, (size_t)512 * 2048, wz, 2048,
                b2, 512,
                O116_2 + (size_t)z * MS512, nullptr, 8, 0,
                Ob2 + (size_t)z * MS512, 0, 512, M_PAD);
        }
        // ---- LN2 + pair sum -> output ----
        k_ln2pair<<<3360, 256, 0, stream>>>(Ob2, g2, be2, pr ? outv : outt,
                                            pr ? 0 : 1, pr ? 2 : 3);
    }
}

// Round 6
// 828.383 us; speedup vs baseline: 9.9378x; 1.0540x over previous
//
#include <hip/hip_runtime.h>
#include <math.h>

#define M_REAL 13320
#define M_PAD  13440          // 105 * 128
#define B_BATCH 240
#define LN_EPS 1e-5f

#define MS512  ((size_t)M_PAD * 512)
#define MS2048 ((size_t)M_PAD * 2048)

typedef __attribute__((ext_vector_type(8))) short short8;   // bf16x8 frag (4 VGPR)
typedef __attribute__((ext_vector_type(4))) float f32x4;    // MFMA acc

__device__ __forceinline__ ushort f2bf(float f) {
    unsigned u = __float_as_uint(f);
    u += 0x7FFFu + ((u >> 16) & 1u);           // RNE
    return (ushort)(u >> 16);
}
__device__ __forceinline__ float bf2f(ushort h) {
    return __uint_as_float(((unsigned)h) << 16);
}
__device__ __forceinline__ int sel4(int4 v, int z) {
    return z == 0 ? v.x : z == 1 ? v.y : z == 2 ? v.z : v.w;
}

typedef __attribute__((address_space(3))) unsigned int lds_u32;
typedef __attribute__((address_space(1))) unsigned int glb_u32;
__device__ __forceinline__ void gl_lds16(const ushort* g, ushort* l) {
    __builtin_amdgcn_global_load_lds((glb_u32*)g, (lds_u32*)l, 16, 0, 0);
}

// ---------------- offsets ----------------
__global__ void k_offsets(const int* __restrict__ num_objs, int* __restrict__ offs) {
    if (threadIdx.x == 0) {
        int acc = 0;
        for (int b = 0; b < B_BATCH; ++b) { offs[b] = acc; acc += num_objs[b]; }
    }
}

// ---------------- f32 [M_REAL,512] -> bf16 [M_PAD,512], zero pad rows -------
__global__ __launch_bounds__(256)
void k_cvt_in(const float* __restrict__ src, ushort* __restrict__ dst) {
    int idx = blockIdx.x * 256 + threadIdx.x;   // one thread = 8 elems
    int row = idx >> 6;
    short8 o;
    if (row < M_REAL) {
        const float4* s = (const float4*)src + (size_t)idx * 2;
        float4 a = s[0], b = s[1];
        o[0] = (short)f2bf(a.x); o[1] = (short)f2bf(a.y);
        o[2] = (short)f2bf(a.z); o[3] = (short)f2bf(a.w);
        o[4] = (short)f2bf(b.x); o[5] = (short)f2bf(b.y);
        o[6] = (short)f2bf(b.z); o[7] = (short)f2bf(b.w);
    } else {
        o = (short8)0;
    }
    ((short8*)dst)[idx] = o;
}

// ---------------- bias concat: bqkv[e][1536] = cat(bq,bk,bv) -----------------
__global__ void k_cat_bias(const float* __restrict__ bq, const float* __restrict__ bk,
                           const float* __restrict__ bv, float* __restrict__ out) {
    int idx = blockIdx.x * 256 + threadIdx.x;
    if (idx >= 4 * 1536) return;
    int e = idx / 1536, c = idx - e * 1536;
    float v = (c < 512) ? bq[e * 512 + c] : (c < 1024) ? bk[e * 512 + c - 512]
                                                       : bv[e * 512 + c - 1024];
    out[idx] = v;
}

// ---------------- weight transpose+cvt: f32 [R,C] -> bf16 [C,R] --------------
__global__ __launch_bounds__(256)
void k_wt(const float* __restrict__ src, ushort* __restrict__ dst, int R, int C,
          size_t dstStride, size_t dstOff) {
    __shared__ float t[32][33];
    const float* s = src + (size_t)blockIdx.z * R * C;
    ushort* d = dst + (size_t)blockIdx.z * dstStride + dstOff;
    int tx = threadIdx.x & 31, ty = threadIdx.x >> 5;   // 32 x 8
    int r0 = blockIdx.y * 32, c0 = blockIdx.x * 32;
#pragma unroll
    for (int i = 0; i < 4; ++i)
        t[ty + i * 8][tx] = s[(size_t)(r0 + ty + i * 8) * C + c0 + tx];
    __syncthreads();
#pragma unroll
    for (int i = 0; i < 4; ++i)
        d[(size_t)(c0 + ty + i * 8) * R + r0 + tx] = f2bf(t[tx][ty + i * 8]);
}

// ---------------- bf16 MFMA GEMM: 2-phase double-buffered K-loop -------------
// T3 "minimum 2-phase": STAGE(t+1) issued BEFORE compute(t); ONE barrier per
// K-step (compiler's vmcnt(0)+lgkmcnt(0) at __syncthreads drains the prefetch
// that was in flight during compute). LDS 2x32KB -> 2 blocks/CU.
enum { EPI_BF16 = 0, EPI_BF16_RELU = 1, EPI_F32_RESF32 = 2, EPI_F32_RESBF16 = 3 };

template<int MODE>
__global__ __launch_bounds__(256)
void k_gemm16(const ushort* __restrict__ A, const ushort* __restrict__ A2, int bySplit,
              size_t zA, int lda,
              const ushort* __restrict__ Wb, size_t wSize, int4 widx, int K,
              const float* __restrict__ biasB, int biasStride,
              const void* __restrict__ resv, const void* __restrict__ resv2,
              int resSplit, size_t zRes,
              void* __restrict__ Cv, size_t zC, int ldc, int Mreal) {
    __shared__ ushort As[2][128 * 64];
    __shared__ ushort Bs[2][128 * 64];
    const int tid = threadIdx.x;

    // ---- XCD-chunked remap: dispatch ordinal d -> contiguous work per XCD ----
    const int NX = gridDim.x, NY = gridDim.y;
    const int NB = NX * NY * (int)gridDim.z;
    int d = blockIdx.x + NX * (blockIdx.y + NY * blockIdx.z);
    int qq = NB >> 3, rr = NB & 7;
    int xcd = d & 7, idx = d >> 3;
    int work = (xcd < rr ? xcd * (qq + 1) : rr * (qq + 1) + (xcd - rr) * qq) + idx;
    const int z = work / (NX * NY);
    int rem = work - z * (NX * NY);
    const int panel = rem / NY;            // row-panel index (col-fastest within panel)
    const int colb = rem - panel * NY;
    const int row0 = panel * 128;
    const int col0 = colb * 128;

    const ushort* Ause = ((colb < bySplit) ? A : A2) + (size_t)z * zA;
    const ushort* Wt = Wb + (size_t)sel4(widx, z) * wSize;
    const float* bias = biasB + (size_t)sel4(widx, z) * biasStride;
    const int zi = (z < resSplit) ? z : z - resSplit;
    const float*  resF = (const float*)((z < resSplit) ? resv : resv2) + (size_t)zi * zRes;
    const ushort* resH = (const ushort*)((z < resSplit) ? resv : resv2) + (size_t)zi * zRes;
    ushort* C16 = (ushort*)Cv + (size_t)z * zC;
    float*  C32 = (float*)Cv + (size_t)z * zC;

    const int lane = tid & 63, wid = tid >> 6;
    const int wr = wid >> 1, wc = wid & 1;
    const int fr = lane & 15, fq = lane >> 4;

    int srow[4], scol[4], soff[4];
#pragma unroll
    for (int r = 0; r < 4; ++r) {
        int off = tid * 16 + r * 4096;
        int row = off >> 7;
        int cp  = (off >> 4) & 7;
        soff[r] = off;
        srow[r] = row;
        scol[r] = (cp ^ (row & 7)) * 8;
    }

    f32x4 acc[4][4];
#pragma unroll
    for (int m = 0; m < 4; ++m)
#pragma unroll
        for (int n = 0; n < 4; ++n) acc[m][n] = (f32x4){0.f, 0.f, 0.f, 0.f};

    const int nk = K >> 6;

    // prologue: stage K-tile 0 into buffer 0
    {
#pragma unroll
        for (int r = 0; r < 4; ++r)
            gl_lds16(Ause + (size_t)(row0 + srow[r]) * lda + scol[r],
                     (ushort*)((char*)As[0] + soff[r]));
#pragma unroll
        for (int r = 0; r < 4; ++r)
            gl_lds16(Wt + (size_t)(col0 + srow[r]) * K + scol[r],
                     (ushort*)((char*)Bs[0] + soff[r]));
    }
    __syncthreads();

    for (int kt = 0; kt < nk; ++kt) {
        const int cur = kt & 1;
        // ---- issue prefetch of next K-tile into other buffer (in flight
        //      during this tile's compute; drained by end-of-step barrier) ----
        if (kt + 1 < nk) {
            const int nxt = cur ^ 1;
            const int k0 = (kt + 1) << 6;
#pragma unroll
            for (int r = 0; r < 4; ++r)
                gl_lds16(Ause + (size_t)(row0 + srow[r]) * lda + k0 + scol[r],
                         (ushort*)((char*)As[nxt] + soff[r]));
#pragma unroll
            for (int r = 0; r < 4; ++r)
                gl_lds16(Wt + (size_t)(col0 + srow[r]) * K + k0 + scol[r],
                         (ushort*)((char*)Bs[nxt] + soff[r]));
        }
        // ---- compute current tile ----
#pragma unroll
        for (int kk = 0; kk < 2; ++kk) {
            short8 av[4], bv[4];
#pragma unroll
            for (int m = 0; m < 4; ++m) {
                int row = wr * 64 + m * 16 + fr;
                int byte = row * 128 + (((kk * 4 + fq) ^ (row & 7)) << 4);
                av[m] = *(const short8*)((const char*)As[cur] + byte);
            }
#pragma unroll
            for (int n = 0; n < 4; ++n) {
                int row = wc * 64 + n * 16 + fr;
                int byte = row * 128 + (((kk * 4 + fq) ^ (row & 7)) << 4);
                bv[n] = *(const short8*)((const char*)Bs[cur] + byte);
            }
#pragma unroll
            for (int m = 0; m < 4; ++m)
#pragma unroll
                for (int n = 0; n < 4; ++n)
                    acc[m][n] = __builtin_amdgcn_mfma_f32_16x16x32_bf16(av[m], bv[n], acc[m][n], 0, 0, 0);
        }
        // one barrier per K-step (drains prefetch + orders buffer reuse)
        if (kt + 1 < nk) __syncthreads();
    }

    // epilogue: C/D layout col=lane&15, row=(lane>>4)*4+i
#pragma unroll
    for (int m = 0; m < 4; ++m) {
#pragma unroll
        for (int n = 0; n < 4; ++n) {
            int cN = col0 + wc * 64 + n * 16 + fr;
            float bsv = bias[cN];
#pragma unroll
            for (int i = 0; i < 4; ++i) {
                int r = row0 + wr * 64 + m * 16 + fq * 4 + i;
                size_t oidx = (size_t)r * ldc + cN;
                float v = acc[m][n][i] + bsv;
                if (MODE == EPI_BF16) {
                    C16[oidx] = f2bf(v);
                } else if (MODE == EPI_BF16_RELU) {
                    C16[oidx] = f2bf(fmaxf(v, 0.f));
                } else if (MODE == EPI_F32_RESF32) {
                    if (r < Mreal) v += resF[oidx];
                    C32[oidx] = v;
                } else {
                    v += bf2f(resH[oidx]);
                    C32[oidx] = v;
                }
            }
        }
    }
}

// ---------------- MFMA segment attention (verified) --------------------------
#define KS_STRIDE 72
#define VT_STRIDE 104
#define PL_STRIDE 104

__global__ __launch_bounds__(256)
void k_attn_mfma(const ushort* __restrict__ QKV, const int* __restrict__ offs,
                 const int* __restrict__ num_objs, ushort* __restrict__ CTX) {
    __shared__ __attribute__((aligned(16))) ushort Ks[96 * KS_STRIDE];
    __shared__ __attribute__((aligned(16))) ushort Vt[64 * VT_STRIDE];
    __shared__ __attribute__((aligned(16))) ushort Pl[64 * PL_STRIDE];
    const int b = blockIdx.x, h = blockIdx.y;
    const int L = num_objs[b], off = offs[b];
    const int tid = threadIdx.x;
    const int lane = tid & 63, wid = tid >> 6;
    const int fr = lane & 15, fq = lane >> 4;

#pragma unroll
    for (int pass = 0; pass < 3; ++pass) {
        int j = pass * 32 + (tid >> 3);
        int d0 = (tid & 7) * 8;
        short8 kv = (short8)0, vv = (short8)0;
        if (j < L) {
            size_t base = (size_t)(off + j) * 1536 + h * 64 + d0;
            kv = *(const short8*)(QKV + base + 512);
            vv = *(const short8*)(QKV + base + 1024);
        }
        *(short8*)&Ks[j * KS_STRIDE + d0] = kv;
#pragma unroll
        for (int e = 0; e < 8; ++e) Vt[(d0 + e) * VT_STRIDE + j] = (ushort)vv[e];
    }
    __syncthreads();

    const int nkb = (L + 15) >> 4;
    const int nkc = (nkb + 1) >> 1;

    for (int qb = wid; qb < 6; qb += 4) {
        if (qb >= nkb) continue;
        const int q0 = qb * 16;
        const int qrow = q0 + fr;
        const int qc = (qrow < L) ? qrow : (L - 1);
        const ushort* qbase = QKV + (size_t)(off + qc) * 1536 + h * 64 + fq * 8;
        short8 qf0 = *(const short8*)qbase;
        short8 qf1 = *(const short8*)(qbase + 32);

        f32x4 st[6];
#pragma unroll 6
        for (int kb = 0; kb < nkb; ++kb) {
            short8 a0 = *(const short8*)&Ks[(kb * 16 + fr) * KS_STRIDE + fq * 8];
            short8 a1 = *(const short8*)&Ks[(kb * 16 + fr) * KS_STRIDE + 32 + fq * 8];
            f32x4 acc = (f32x4){0.f, 0.f, 0.f, 0.f};
            acc = __builtin_amdgcn_mfma_f32_16x16x32_bf16(a0, qf0, acc, 0, 0, 0);
            acc = __builtin_amdgcn_mfma_f32_16x16x32_bf16(a1, qf1, acc, 0, 0, 0);
            st[kb] = acc;
        }

        float m = -1e30f;
#pragma unroll 6
        for (int kb = 0; kb < nkb; ++kb)
#pragma unroll
            for (int i = 0; i < 4; ++i) {
                int k = kb * 16 + fq * 4 + i;
                if (k < L) m = fmaxf(m, st[kb][i] * 0.125f);
            }
        m = fmaxf(m, __shfl_xor(m, 16));
        m = fmaxf(m, __shfl_xor(m, 32));
        float sum = 0.f;
        float pv[6][4];
#pragma unroll
        for (int kb = 0; kb < 6; ++kb)
#pragma unroll
            for (int i = 0; i < 4; ++i) {
                float p = 0.f;
                if (kb < nkb) {
                    int k = kb * 16 + fq * 4 + i;
                    if (k < L) p = __expf(st[kb][i] * 0.125f - m);
                }
                pv[kb][i] = p;
                sum += p;
            }
        sum += __shfl_xor(sum, 16);
        sum += __shfl_xor(sum, 32);
        float inv = 1.f / sum;

        ushort* prow = &Pl[(wid * 16 + fr) * PL_STRIDE];
#pragma unroll
        for (int kb = 0; kb < 6; ++kb) {
            unsigned lo = (unsigned)f2bf(pv[kb][0]) | ((unsigned)f2bf(pv[kb][1]) << 16);
            unsigned hi = (unsigned)f2bf(pv[kb][2]) | ((unsigned)f2bf(pv[kb][3]) << 16);
            *(unsigned*)&prow[kb * 16 + fq * 4]     = lo;
            *(unsigned*)&prow[kb * 16 + fq * 4 + 2] = hi;
        }

        f32x4 ct[4];
#pragma unroll
        for (int db = 0; db < 4; ++db) ct[db] = (f32x4){0.f, 0.f, 0.f, 0.f};
        const ushort* prd = &Pl[(wid * 16 + fr) * PL_STRIDE];
#pragma unroll 3
        for (int kc = 0; kc < nkc; ++kc) {
            short8 pf = *(const short8*)&prd[kc * 32 + fq * 8];
#pragma unroll
            for (int db = 0; db < 4; ++db) {
                short8 vf = *(const short8*)&Vt[(db * 16 + fr) * VT_STRIDE + kc * 32 + fq * 8];
                ct[db] = __builtin_amdgcn_mfma_f32_16x16x32_bf16(vf, pf, ct[db], 0, 0, 0);
            }
        }

        if (qrow < L) {
            ushort* crow = CTX + (size_t)(off + qrow) * 512 + h * 64;
#pragma unroll
            for (int db = 0; db < 4; ++db) {
                ushort4 o;
                o.x = f2bf(ct[db][0] * inv);
                o.y = f2bf(ct[db][1] * inv);
                o.z = f2bf(ct[db][2] * inv);
                o.w = f2bf(ct[db][3] * inv);
                *(ushort4*)&crow[db * 16 + fq * 4] = o;
            }
        }
    }
}

// ---------------- LayerNorm helpers (one wave per row) -----------------------
__device__ __forceinline__ void ln_row8(const float* __restrict__ X, const float* __restrict__ g,
                                        const float* __restrict__ be, int lane, float* o) {
    const float4* x4 = (const float4*)X;
    float4 v0 = x4[2 * lane], v1 = x4[2 * lane + 1];
    float s = v0.x + v0.y + v0.z + v0.w + v1.x + v1.y + v1.z + v1.w;
    for (int t = 32; t > 0; t >>= 1) s += __shfl_xor(s, t);
    float mean = s * (1.f / 512.f);
    float dd[8] = {v0.x - mean, v0.y - mean, v0.z - mean, v0.w - mean,
                   v1.x - mean, v1.y - mean, v1.z - mean, v1.w - mean};
    float vs = 0.f;
#pragma unroll
    for (int i = 0; i < 8; ++i) vs += dd[i] * dd[i];
    for (int t = 32; t > 0; t >>= 1) vs += __shfl_xor(vs, t);
    float rstd = rsqrtf(vs * (1.f / 512.f) + LN_EPS);
    const float4* g4 = (const float4*)g;
    const float4* b4 = (const float4*)be;
    float4 ga = g4[2 * lane], gb = g4[2 * lane + 1];
    float4 ba = b4[2 * lane], bb = b4[2 * lane + 1];
    o[0] = dd[0] * rstd * ga.x + ba.x;  o[1] = dd[1] * rstd * ga.y + ba.y;
    o[2] = dd[2] * rstd * ga.z + ba.z;  o[3] = dd[3] * rstd * ga.w + ba.w;
    o[4] = dd[4] * rstd * gb.x + bb.x;  o[5] = dd[5] * rstd * gb.y + bb.y;
    o[6] = dd[6] * rstd * gb.z + bb.z;  o[7] = dd[7] * rstd * gb.w + bb.w;
}

// LN1 batched over z encoders (z=blockIdx.y), bf16 out. 4 rows per block.
__global__ __launch_bounds__(256)
void k_ln1(const float* __restrict__ Xb, const float* __restrict__ gB,
           const float* __restrict__ beB, ushort* __restrict__ outB, int4 widx) {
    int e = blockIdx.y;
    int row = blockIdx.x * 4 + (threadIdx.x >> 6);
    int lane = threadIdx.x & 63;
    int pi = sel4(widx, e);
    float o[8];
    ln_row8(Xb + (size_t)e * MS512 + (size_t)row * 512, gB + pi * 512, beB + pi * 512, lane, o);
    short8 o8;
#pragma unroll
    for (int i = 0; i < 8; ++i) o8[i] = (short)f2bf(o[i]);
    ((short8*)(outB + (size_t)e * MS512 + (size_t)row * 512))[lane] = o8;
}

// LN2 + pair sum: dst = LN(Ob2[0]; pA) + LN(Ob2[1]; pB)
__global__ __launch_bounds__(256)
void k_ln2pair(const float* __restrict__ Ob2, const float* __restrict__ gB,
               const float* __restrict__ beB, float* __restrict__ dst,
               int pA, int pB) {
    int row = blockIdx.x * 4 + (threadIdx.x >> 6);
    int lane = threadIdx.x & 63;
    float oA[8], oB[8];
    ln_row8(Ob2 + (size_t)row * 512,         gB + pA * 512, beB + pA * 512, lane, oA);
    ln_row8(Ob2 + MS512 + (size_t)row * 512, gB + pB * 512, beB + pB * 512, lane, oB);
    if (row < M_REAL) {
        float* drow = dst + (size_t)row * 512;
        float4 s0, s1;
        s0.x = oA[0] + oB[0]; s0.y = oA[1] + oB[1]; s0.z = oA[2] + oB[2]; s0.w = oA[3] + oB[3];
        s1.x = oA[4] + oB[4]; s1.y = oA[5] + oB[5]; s1.z = oA[6] + oB[6]; s1.w = oA[7] + oB[7];
        ((float4*)drow)[2 * lane] = s0;
        ((float4*)drow)[2 * lane + 1] = s1;
    }
}

// ---------------- driver ------------------------------------------------------
extern "C" void kernel_launch(void* const* d_in, const int* in_sizes, int n_in,
                              void* d_out, int out_size, void* d_ws, size_t ws_size,
                              hipStream_t stream) {
    const float* vis = (const float*)d_in[0];
    const float* txt = (const float*)d_in[1];
    const float* Wq  = (const float*)d_in[2];
    const float* bq  = (const float*)d_in[3];
    const float* Wk  = (const float*)d_in[4];
    const float* bk  = (const float*)d_in[5];
    const float* Wv  = (const float*)d_in[6];
    const float* bv  = (const float*)d_in[7];
    const float* Wo  = (const float*)d_in[8];
    const float* bo  = (const float*)d_in[9];
    const float* g1  = (const float*)d_in[10];
    const float* be1 = (const float*)d_in[11];
    const float* W1  = (const float*)d_in[12];
    const float* b1  = (const float*)d_in[13];
    const float* W2  = (const float*)d_in[14];
    const float* b2  = (const float*)d_in[15];
    const float* g2  = (const float*)d_in[16];
    const float* be2 = (const float*)d_in[17];
    const int* num_objs = (const int*)d_in[18];

    // ---- workspace (aliased unions): 190.3 MB total (< proven-good 203 MB) --
    char* p = (char*)d_ws;
    ushort* QKV16  = (ushort*)p;               // U1: [M_PAD][1536] bf16 (QKV phase)
    ushort* H16    = (ushort*)p;               // U1: [M_PAD][2048] bf16 (FFN phase)
    p += (size_t)M_PAD * 2048 * 2;             // 55.05 MB
    ushort* CTX2   = (ushort*)p;               // U2: [2][M_PAD][512] bf16 (attn out)
    ushort* O116_2 = (ushort*)p;               // U2 alias: LN1 out (CTX dead after Wo)
    p += (size_t)2 * MS512 * 2;                // 27.5 MB
    float*  Ob2    = (float*)p;                // U3: [2][M_PAD][512] f32 (Wo out / FFN2 out)
    p += (size_t)2 * MS512 * 4;                // 55.05 MB
    ushort* vis16  = (ushort*)p;  p += MS512 * 2;
    ushort* txt16  = (ushort*)p;  p += MS512 * 2;
    ushort* wqkv16 = (ushort*)p;  p += (size_t)4 * 1536 * 512 * 2;
    ushort* wo16   = (ushort*)p;  p += (size_t)4 * 512 * 512 * 2;
    ushort* w116   = (ushort*)p;  p += (size_t)4 * 2048 * 512 * 2;
    ushort* w216   = (ushort*)p;  p += (size_t)4 * 512 * 2048 * 2;
    float*  bqkv   = (float*)p;   p += (size_t)4 * 1536 * 4;
    int*    offs   = (int*)p;     p += 1024;

    float* outv = (float*)d_out;
    float* outt = outv + (size_t)M_REAL * 512;

    k_offsets<<<1, 64, 0, stream>>>(num_objs, offs);
    k_cvt_in<<<3360, 256, 0, stream>>>(vis, vis16);
    k_cvt_in<<<3360, 256, 0, stream>>>(txt, txt16);
    k_cat_bias<<<24, 256, 0, stream>>>(bq, bk, bv, bqkv);
    // wqkv[e] = [1536][512]: rows 0-511 Wq^T, 512-1023 Wk^T, 1024-1535 Wv^T
    k_wt<<<dim3(16, 16, 4), 256, 0, stream>>>(Wq, wqkv16, 512, 512, (size_t)1536 * 512, 0);
    k_wt<<<dim3(16, 16, 4), 256, 0, stream>>>(Wk, wqkv16, 512, 512, (size_t)1536 * 512, (size_t)512 * 512);
    k_wt<<<dim3(16, 16, 4), 256, 0, stream>>>(Wv, wqkv16, 512, 512, (size_t)1536 * 512, (size_t)1024 * 512);
    k_wt<<<dim3(16, 16, 4), 256, 0, stream>>>(Wo, wo16, 512, 512, (size_t)512 * 512, 0);
    k_wt<<<dim3(64, 16, 4), 256, 0, stream>>>(W1, w116, 512, 2048, (size_t)2048 * 512, 0);
    k_wt<<<dim3(16, 64, 4), 256, 0, stream>>>(W2, w216, 2048, 512, (size_t)512 * 2048, 0);

    // e order: 0=tsa(txt,txt,p1) 1=tca(txt,vis,p3) 2=vsa(vis,vis,p0) 3=vca(vis,txt,p2)
    const int perm[4] = {1, 3, 0, 2};
    const ushort* qsrc[4]  = {txt16, txt16, vis16, vis16};
    const ushort* kvsrc[4] = {txt16, vis16, vis16, txt16};

    for (int pr = 0; pr < 2; ++pr) {
        // ---- QKV (fused N=1536) + attention, per encoder of the pair ----
        for (int z = 0; z < 2; ++z) {
            int e = 2 * pr + z;
            int4 wz = make_int4(perm[e], perm[e], perm[e], perm[e]);
            k_gemm16<EPI_BF16><<<dim3(105, 12, 1), 256, 0, stream>>>(
                qsrc[e], kvsrc[e], 4, 0, 512,
                wqkv16, (size_t)1536 * 512, wz, 512,
                bqkv, 1536,
                nullptr, nullptr, 8, 0,
                QKV16, 0, 1536, M_PAD);
            k_attn_mfma<<<dim3(B_BATCH, 8), 256, 0, stream>>>(
                QKV16, offs, num_objs, CTX2 + (size_t)z * MS512);
        }
        // ---- Wo (z=2): Ob2[z] = CTX2[z]@Wo + bo + q_in (f32) ----
        int4 wzp = make_int4(perm[2 * pr], perm[2 * pr + 1], 0, 0);
        const float* resq = pr ? vis : txt;
        k_gemm16<EPI_F32_RESF32><<<dim3(105, 4, 2), 256, 0, stream>>>(
            CTX2, CTX2, 99, MS512, 512,
            wo16, (size_t)512 * 512, wzp, 512,
            bo, 512,
            resq, resq, 2, 0,
            Ob2, MS512, 512, M_REAL);
        // ---- LN1 (z=2) -> bf16 (overwrites CTX alias) ----
        k_ln1<<<dim3(3360, 2), 256, 0, stream>>>(Ob2, g1, be1, O116_2, wzp);
        // ---- FFN per encoder (H16 single-buffer) ----
        for (int z = 0; z < 2; ++z) {
            int e = 2 * pr + z;
            int4 wz = make_int4(perm[e], perm[e], perm[e], perm[e]);
            k_gemm16<EPI_BF16_RELU><<<dim3(105, 16, 1), 256, 0, stream>>>(
                O116_2 + (size_t)z * MS512, O116_2, 99, 0, 512,
                w116, (size_t)2048 * 512, wz, 512,
                b1, 2048,
                nullptr, nullptr, 8, 0,
                H16, 0, 2048, M_PAD);
            k_gemm16<EPI_F32_RESBF16><<<dim3(105, 4, 1), 256, 0, stream>>>(
                H16, H16, 99, 0, 2048,
                w216, (size_t)512 * 2048, wz, 2048,
                b2, 512,
                O116_2 + (size_t)z * MS512, nullptr, 8, 0,
                Ob2 + (size_t)z * MS512, 0, 512, M_PAD);
        }
        // ---- LN2 + pair sum -> output ----
        k_ln2pair<<<3360, 256, 0, stream>>>(Ob2, g2, be2, pr ? outv : outt,
                                            pr ? 0 : 1, pr ? 2 : 3);
    }
}